// Round 1
// baseline (3457.648 us; speedup 1.0000x reference)
//
#include <hip/hip_runtime.h>
#include <math.h>

// Bamba-9B mixer, b=1 s=2048, all fp32 round-0 implementation.
static constexpr int kS     = 2048;
static constexpr int kHID   = 2048;
static constexpr int kI     = 4096;
static constexpr int kH     = 64;
static constexpr int kP     = 64;
static constexpr int kN     = 128;
static constexpr int kConv  = 4352;   // I + 2*G*N
static constexpr int kProj  = 8512;   // I + CONV + H
static constexpr int kChunk = 256;
static constexpr int kNC    = 8;
static constexpr float kEps = 1e-5f;

__device__ __forceinline__ float4 f4fma(float a, float4 b, float4 c) {
    c.x += a * b.x; c.y += a * b.y; c.z += a * b.z; c.w += a * b.w; return c;
}
__device__ __forceinline__ float siluf(float x) {
    return x / (1.f + __expf(-x));
}

// ---------------- NT fp32 GEMM: C[M,N] = A[M,K] * B[N,K]^T ------------------
// BM=128 BN=64 BK=16, 256 threads, 8x4 per thread. All dims divide exactly.
__global__ __launch_bounds__(256)
void gemm_nt_f32(const float* __restrict__ A, const float* __restrict__ B,
                 float* __restrict__ C, int M, int N, int K)
{
    __shared__ float As[16][132];   // [k][m], pad 4 keeps f4 alignment, 2-way max
    __shared__ float Bs[16][68];    // [k][n]
    const int m0 = blockIdx.y * 128;
    const int n0 = blockIdx.x * 64;
    const int tid = threadIdx.x;
    const int tm = tid >> 4;        // 16 groups of 8 rows
    const int tn = tid & 15;        // 16 groups of 4 cols
    float4 acc[8];
#pragma unroll
    for (int i = 0; i < 8; ++i) acc[i] = make_float4(0.f, 0.f, 0.f, 0.f);

    for (int k0 = 0; k0 < K; k0 += 16) {
#pragma unroll
        for (int i = 0; i < 2; ++i) {           // A tile: 128x16 = 512 f4
            int f = tid + 256 * i;
            int r = f >> 2, kq = (f & 3) * 4;
            float4 v = *(const float4*)&A[(size_t)(m0 + r) * K + k0 + kq];
            As[kq + 0][r] = v.x; As[kq + 1][r] = v.y;
            As[kq + 2][r] = v.z; As[kq + 3][r] = v.w;
        }
        {                                       // B tile: 64x16 = 256 f4
            int r = tid >> 2, kq = (tid & 3) * 4;
            float4 v = *(const float4*)&B[(size_t)(n0 + r) * K + k0 + kq];
            Bs[kq + 0][r] = v.x; Bs[kq + 1][r] = v.y;
            Bs[kq + 2][r] = v.z; Bs[kq + 3][r] = v.w;
        }
        __syncthreads();
#pragma unroll
        for (int k = 0; k < 16; ++k) {
            float4 a0 = *(const float4*)&As[k][tm * 8];
            float4 a1 = *(const float4*)&As[k][tm * 8 + 4];
            float4 b  = *(const float4*)&Bs[k][tn * 4];
            float a_[8] = {a0.x, a0.y, a0.z, a0.w, a1.x, a1.y, a1.z, a1.w};
#pragma unroll
            for (int i = 0; i < 8; ++i) {
                acc[i].x += a_[i] * b.x; acc[i].y += a_[i] * b.y;
                acc[i].z += a_[i] * b.z; acc[i].w += a_[i] * b.w;
            }
        }
        __syncthreads();
    }
#pragma unroll
    for (int i = 0; i < 8; ++i) {
        int m = m0 + tm * 8 + i;
        *(float4*)&C[(size_t)m * N + n0 + tn * 4] = acc[i];
    }
}

// --------------- depthwise causal conv (K=4) + bias + SiLU ------------------
__global__ __launch_bounds__(256)
void conv_silu_k(const float* __restrict__ proj, const float* __restrict__ cw,
                 const float* __restrict__ cb, float* __restrict__ convout)
{
    int idx = blockIdx.x * 256 + threadIdx.x;   // kS*kConv total, d fastest
    int d = idx % kConv, t = idx / kConv;
    float acc = cb[d];
#pragma unroll
    for (int k = 0; k < 4; ++k) {
        int ts = t + k - 3;
        float u = (ts >= 0) ? proj[(size_t)ts * kProj + kI + d] : 0.f;
        acc += u * cw[d * 4 + k];
    }
    convout[idx] = siluf(acc);
}

// --------------- dt = softplus(dt_raw + bias); per-chunk cumsum(dt*A) -------
// one block per (chunk, head); 256-thread inclusive scan
__global__ __launch_bounds__(256)
void dt_cumsum_k(const float* __restrict__ proj, const float* __restrict__ dt_bias,
                 const float* __restrict__ A_log, float* __restrict__ dt,
                 float* __restrict__ acum)
{
    __shared__ float wsum[4];
    const int c = blockIdx.x >> 6, h = blockIdx.x & 63;
    const int l = threadIdx.x, t = c * kChunk + l;
    float a = -expf(A_log[h]);
    float z = proj[(size_t)t * kProj + kI + kConv + h] + dt_bias[h];
    float d = (z > 20.f) ? z : log1pf(expf(z));
    dt[t * kH + h] = d;
    float v = d * a;
    int lane = l & 63, w = l >> 6;
#pragma unroll
    for (int off = 1; off < 64; off <<= 1) {
        float u = __shfl_up(v, off);
        if (lane >= off) v += u;
    }
    if (lane == 63) wsum[w] = v;
    __syncthreads();
    float add = 0.f;
    for (int i = 0; i < w; ++i) add += wsum[i];
    acum[t * kH + h] = v + add;
}

// --------------- per-chunk end states: st[p,n] = sum_l dte_l B[l,n] x[l,p] --
// one block per (chunk, head); thread = (p, n-quarter), 8xf4 accumulators
__global__ __launch_bounds__(256)
void states_k(const float* __restrict__ conv, const float* __restrict__ dt,
              const float* __restrict__ acum, float* __restrict__ states)
{
    __shared__ float Bl[64][132];
    __shared__ float Xl[64][68];
    __shared__ float Wl[64];
    const int c = blockIdx.x >> 6, h = blockIdx.x & 63;
    const int tid = threadIdx.x;
    const int p = tid & 63, ng = tid >> 6;  // ng uniform per wave -> broadcast reads
    const float aend = acum[(size_t)(c * kChunk + 255) * kH + h];
    float4 acc[8];
#pragma unroll
    for (int i = 0; i < 8; ++i) acc[i] = make_float4(0.f, 0.f, 0.f, 0.f);

    for (int lt = 0; lt < 4; ++lt) {
        int tbase = c * kChunk + lt * 64;
#pragma unroll
        for (int r = 0; r < 8; ++r) {       // B: 64x128 = 2048 f4
            int f = tid + 256 * r;
            int ll = f >> 5, c4 = (f & 31) * 4;
            *(float4*)&Bl[ll][c4] =
                *(const float4*)&conv[(size_t)(tbase + ll) * kConv + kI + c4];
        }
#pragma unroll
        for (int r = 0; r < 4; ++r) {       // X: 64x64 = 1024 f4
            int f = tid + 256 * r;
            int ll = f >> 4, c4 = (f & 15) * 4;
            *(float4*)&Xl[ll][c4] =
                *(const float4*)&conv[(size_t)(tbase + ll) * kConv + h * kP + c4];
        }
        if (tid < 64) {
            int t = tbase + tid;
            Wl[tid] = __expf(aend - acum[(size_t)t * kH + h]) * dt[(size_t)t * kH + h];
        }
        __syncthreads();
        for (int ll = 0; ll < 64; ++ll) {
            float xv = Xl[ll][p] * Wl[ll];
#pragma unroll
            for (int j = 0; j < 8; ++j) {
                float4 b = *(const float4*)&Bl[ll][ng * 32 + j * 4];
                acc[j] = f4fma(xv, b, acc[j]);
            }
        }
        __syncthreads();
    }
    size_t base = ((size_t)(c * kH + h) * kP + p) * kN + ng * 32;
#pragma unroll
    for (int j = 0; j < 8; ++j) *(float4*)&states[base + j * 4] = acc[j];
}

// --------------- sequential inter-chunk recurrence (8 chunks) ---------------
__global__ __launch_bounds__(256)
void scan_k(const float* __restrict__ states, const float* __restrict__ acum,
            float* __restrict__ prev)
{
    const int h = blockIdx.x >> 3, seg = blockIdx.x & 7;
    const int e = (seg * 256 + threadIdx.x) * 4;     // [0,8192)
    float4 carry = make_float4(0.f, 0.f, 0.f, 0.f);
    for (int c = 0; c < kNC; ++c) {
        size_t base = (size_t)(c * kH + h) * (kP * kN);
        *(float4*)&prev[base + e] = carry;           // emit state at chunk start
        float dec = __expf(acum[(size_t)(c * kChunk + 255) * kH + h]);
        float4 st = *(const float4*)&states[base + e];
        carry.x = carry.x * dec + st.x; carry.y = carry.y * dec + st.y;
        carry.z = carry.z * dec + st.z; carry.w = carry.w * dec + st.w;
    }
}

// --------------- SSD Y: intra-chunk causal part + inter part + D skip -------
// one block per (chunk, head, 64-row t-tile); 256 threads
// thread = (tr = row 0..63, pc = p-quarter 0..3); acc = 16 floats (4xf4)
__global__ __launch_bounds__(256)
void ssd_y_k(const float* __restrict__ conv, const float* __restrict__ dt,
             const float* __restrict__ acum, const float* __restrict__ prev,
             const float* __restrict__ Dp, float* __restrict__ Y)
{
    __shared__ float Ct[64][132];   // C rows for this t-tile
    __shared__ float Bs[16][132];   // B s-tile
    __shared__ float Xs[16][64];    // x s-tile (reads are 2-way broadcast: free)
    __shared__ float Ws[64][17];    // weighted causal CB tile
    __shared__ float Pl[32][68];    // prev, transposed [n][p]
    __shared__ float At[64];
    __shared__ float sAc[16], sDt[16];

    const int b = blockIdx.x;
    const int q = b & 3, h = (b >> 2) & 63, c = b >> 8;
    const int t0 = q * 64;
    const int tid = threadIdx.x;
    const int tr = tid >> 2, pc = tid & 3;
    const int t = t0 + tr;

#pragma unroll
    for (int r = 0; r < 8; ++r) {       // stage C: 64x128 = 2048 f4
        int f = tid + 256 * r;
        int row = f >> 5, c4 = (f & 31) * 4;
        *(float4*)&Ct[row][c4] =
            *(const float4*)&conv[(size_t)(c * kChunk + t0 + row) * kConv + kI + kN + c4];
    }
    if (tid < 64) At[tid] = acum[(size_t)(c * kChunk + t0 + tid) * kH + h];
    __syncthreads();

    // init: D * x
    const float Dh = Dp[h];
    float4 acc[4];
    const float* xrow = &conv[(size_t)(c * kChunk + t) * kConv + h * kP + pc * 16];
#pragma unroll
    for (int j = 0; j < 4; ++j) {
        float4 x4 = *(const float4*)&xrow[j * 4];
        acc[j] = make_float4(Dh * x4.x, Dh * x4.y, Dh * x4.z, Dh * x4.w);
    }

    // inter-chunk: acc += exp(Acum_t) * C_t . prev[p,:]
    {
        float4 it[4];
#pragma unroll
        for (int j = 0; j < 4; ++j) it[j] = make_float4(0.f, 0.f, 0.f, 0.f);
        size_t pbase = (size_t)(c * kH + h) * (kP * kN);
        for (int nt = 0; nt < 4; ++nt) {
#pragma unroll
            for (int r = 0; r < 8; ++r) {   // transpose-stage 64p x 32n
                int f = tid + 256 * r;
                int n = f & 31, p = f >> 5;
                Pl[n][p] = prev[pbase + (size_t)p * kN + nt * 32 + n];
            }
            __syncthreads();
            for (int n = 0; n < 32; ++n) {
                float cn = Ct[tr][nt * 32 + n];
#pragma unroll
                for (int j = 0; j < 4; ++j) {
                    float4 p4 = *(const float4*)&Pl[n][pc * 16 + j * 4];
                    it[j] = f4fma(cn, p4, it[j]);
                }
            }
            __syncthreads();
        }
        float eA = __expf(At[tr]);
#pragma unroll
        for (int j = 0; j < 4; ++j) {
            acc[j].x += eA * it[j].x; acc[j].y += eA * it[j].y;
            acc[j].z += eA * it[j].z; acc[j].w += eA * it[j].w;
        }
    }

    // intra-chunk causal part, s-tiles of 16
    const int nst = (t0 + 64) >> 4;
    const int scg = pc * 4;             // 4 w-columns per thread
    for (int st = 0; st < nst; ++st) {
#pragma unroll
        for (int r = 0; r < 2; ++r) {   // B: 16x128 = 512 f4
            int f = tid + 256 * r;
            int row = f >> 5, c4 = (f & 31) * 4;
            *(float4*)&Bs[row][c4] =
                *(const float4*)&conv[(size_t)(c * kChunk + st * 16 + row) * kConv + kI + c4];
        }
        {                               // X: 16x64 = 256 f4
            int row = tid >> 4, c4 = (tid & 15) * 4;
            *(float4*)&Xs[row][c4] =
                *(const float4*)&conv[(size_t)(c * kChunk + st * 16 + row) * kConv + h * kP + c4];
        }
        if (tid < 16) {
            int s = c * kChunk + st * 16 + tid;
            sAc[tid] = acum[(size_t)s * kH + h];
            sDt[tid] = dt[(size_t)s * kH + h];
        }
        __syncthreads();
        // w[tr][scg..scg+3] = mask(s<=t) * (C_t.B_s) * exp(Acum_t-Acum_s) * dt_s
        float4 cbv[4];
#pragma unroll
        for (int r = 0; r < 4; ++r) cbv[r] = make_float4(0.f, 0.f, 0.f, 0.f);
        for (int n4 = 0; n4 < 32; ++n4) {
            float4 cv = *(const float4*)&Ct[tr][n4 * 4];
#pragma unroll
            for (int r = 0; r < 4; ++r) {
                float4 bv = *(const float4*)&Bs[scg + r][n4 * 4];
                cbv[r].x += cv.x * bv.x; cbv[r].y += cv.y * bv.y;
                cbv[r].z += cv.z * bv.z; cbv[r].w += cv.w * bv.w;
            }
        }
        float at = At[tr];
#pragma unroll
        for (int r = 0; r < 4; ++r) {
            int s = st * 16 + scg + r;
            float cb = cbv[r].x + cbv[r].y + cbv[r].z + cbv[r].w;
            Ws[tr][scg + r] =
                (s <= t) ? cb * __expf(at - sAc[scg + r]) * sDt[scg + r] : 0.f;
        }
        __syncthreads();
        for (int sc = 0; sc < 16; ++sc) {
            float wv = Ws[tr][sc];
#pragma unroll
            for (int j = 0; j < 4; ++j) {
                float4 x4 = *(const float4*)&Xs[sc][pc * 16 + j * 4];
                acc[j] = f4fma(wv, x4, acc[j]);
            }
        }
        __syncthreads();
    }

    float* yrow = &Y[(size_t)(c * kChunk + t) * kI + h * kP + pc * 16];
#pragma unroll
    for (int j = 0; j < 4; ++j) *(float4*)&yrow[j * 4] = acc[j];
}

// --------------- gated RMSNorm (gate before norm), in-place on Y ------------
__global__ __launch_bounds__(256)
void rmsnorm_gate_k(float* __restrict__ Y, const float* __restrict__ proj,
                    const float* __restrict__ nw)
{
    __shared__ float red[4];
    const int t = blockIdx.x, tid = threadIdx.x;
    float* yrow = &Y[(size_t)t * kI];
    const float* grow = &proj[(size_t)t * kProj];
    float v[16];
    float ss = 0.f;
#pragma unroll
    for (int j = 0; j < 4; ++j) {
        int i = (tid + 256 * j) * 4;
        float4 y4 = *(const float4*)&yrow[i];
        float4 g4 = *(const float4*)&grow[i];
        float a = y4.x * siluf(g4.x), bq = y4.y * siluf(g4.y);
        float cq = y4.z * siluf(g4.z), d = y4.w * siluf(g4.w);
        v[j * 4 + 0] = a; v[j * 4 + 1] = bq; v[j * 4 + 2] = cq; v[j * 4 + 3] = d;
        ss += a * a + bq * bq + cq * cq + d * d;
    }
#pragma unroll
    for (int off = 32; off > 0; off >>= 1) ss += __shfl_down(ss, off);
    if ((tid & 63) == 0) red[tid >> 6] = ss;
    __syncthreads();
    float sum = red[0] + red[1] + red[2] + red[3];
    float rr = rsqrtf(sum * (1.f / kI) + kEps);
#pragma unroll
    for (int j = 0; j < 4; ++j) {
        int i = (tid + 256 * j) * 4;
        float4 w4 = *(const float4*)&nw[i];
        float4 o;
        o.x = v[j * 4 + 0] * rr * w4.x; o.y = v[j * 4 + 1] * rr * w4.y;
        o.z = v[j * 4 + 2] * rr * w4.z; o.w = v[j * 4 + 3] * rr * w4.w;
        *(float4*)&yrow[i] = o;
    }
}

extern "C" void kernel_launch(void* const* d_in, const int* in_sizes, int n_in,
                              void* d_out, int out_size, void* d_ws, size_t ws_size,
                              hipStream_t stream)
{
    const float* x       = (const float*)d_in[0];
    const float* W_in    = (const float*)d_in[1];
    const float* conv_w  = (const float*)d_in[2];
    const float* conv_b  = (const float*)d_in[3];
    const float* dt_bias = (const float*)d_in[4];
    const float* A_log   = (const float*)d_in[5];
    const float* Dp      = (const float*)d_in[6];
    const float* norm_w  = (const float*)d_in[7];
    const float* W_out   = (const float*)d_in[8];
    float* out = (float*)d_out;

    // workspace layout (floats). states aliases Y: states die before Y written.
    float* ws     = (float*)d_ws;
    float* proj   = ws;                                   // kS*kProj
    float* conv   = proj + (size_t)kS * kProj;            // kS*kConv
    float* dtb    = conv + (size_t)kS * kConv;            // kS*kH
    float* acum   = dtb + (size_t)kS * kH;                // kS*kH
    float* prev   = acum + (size_t)kS * kH;               // kNC*kH*kP*kN
    float* Y      = prev + (size_t)kNC * kH * kP * kN;    // kS*kI
    float* states = Y;                                    // alias

    dim3 blk(256);
    gemm_nt_f32<<<dim3(kProj / 64, kS / 128), blk, 0, stream>>>(x, W_in, proj, kS, kProj, kHID);
    conv_silu_k<<<(kS * kConv) / 256, blk, 0, stream>>>(proj, conv_w, conv_b, conv);
    dt_cumsum_k<<<kNC * kH, blk, 0, stream>>>(proj, dt_bias, A_log, dtb, acum);
    states_k<<<kNC * kH, blk, 0, stream>>>(conv, dtb, acum, states);
    scan_k<<<kH * 8, blk, 0, stream>>>(states, acum, prev);
    ssd_y_k<<<kNC * kH * 4, blk, 0, stream>>>(conv, dtb, acum, prev, Dp, Y);
    rmsnorm_gate_k<<<kS, blk, 0, stream>>>(Y, proj, norm_w);
    gemm_nt_f32<<<dim3(kHID / 64, kS / 128), blk, 0, stream>>>(Y, W_out, out, kS, kHID, kI);
}

// Round 2
// 1922.600 us; speedup vs baseline: 1.7984x; 1.7984x over previous
//
#include <hip/hip_runtime.h>
#include <math.h>

// Bamba-9B mixer, b=1 s=2048. Round 1: ssd_y rewritten (reg-blocked, no spills).
static constexpr int kS     = 2048;
static constexpr int kHID   = 2048;
static constexpr int kI     = 4096;
static constexpr int kH     = 64;
static constexpr int kP     = 64;
static constexpr int kN     = 128;
static constexpr int kConv  = 4352;   // I + 2*G*N
static constexpr int kProj  = 8512;   // I + CONV + H
static constexpr int kChunk = 256;
static constexpr int kNC    = 8;
static constexpr float kEps = 1e-5f;

__device__ __forceinline__ float4 f4fma(float a, float4 b, float4 c) {
    c.x += a * b.x; c.y += a * b.y; c.z += a * b.z; c.w += a * b.w; return c;
}
__device__ __forceinline__ float siluf(float x) {
    return x / (1.f + __expf(-x));
}

// ---------------- NT fp32 GEMM: C[M,N] = A[M,K] * B[N,K]^T ------------------
__global__ __launch_bounds__(256)
void gemm_nt_f32(const float* __restrict__ A, const float* __restrict__ B,
                 float* __restrict__ C, int M, int N, int K)
{
    __shared__ float As[16][132];
    __shared__ float Bs[16][68];
    const int m0 = blockIdx.y * 128;
    const int n0 = blockIdx.x * 64;
    const int tid = threadIdx.x;
    const int tm = tid >> 4;
    const int tn = tid & 15;
    float4 acc[8];
#pragma unroll
    for (int i = 0; i < 8; ++i) acc[i] = make_float4(0.f, 0.f, 0.f, 0.f);

    for (int k0 = 0; k0 < K; k0 += 16) {
#pragma unroll
        for (int i = 0; i < 2; ++i) {
            int f = tid + 256 * i;
            int r = f >> 2, kq = (f & 3) * 4;
            float4 v = *(const float4*)&A[(size_t)(m0 + r) * K + k0 + kq];
            As[kq + 0][r] = v.x; As[kq + 1][r] = v.y;
            As[kq + 2][r] = v.z; As[kq + 3][r] = v.w;
        }
        {
            int r = tid >> 2, kq = (tid & 3) * 4;
            float4 v = *(const float4*)&B[(size_t)(n0 + r) * K + k0 + kq];
            Bs[kq + 0][r] = v.x; Bs[kq + 1][r] = v.y;
            Bs[kq + 2][r] = v.z; Bs[kq + 3][r] = v.w;
        }
        __syncthreads();
#pragma unroll
        for (int k = 0; k < 16; ++k) {
            float4 a0 = *(const float4*)&As[k][tm * 8];
            float4 a1 = *(const float4*)&As[k][tm * 8 + 4];
            float4 b  = *(const float4*)&Bs[k][tn * 4];
            float a_[8] = {a0.x, a0.y, a0.z, a0.w, a1.x, a1.y, a1.z, a1.w};
#pragma unroll
            for (int i = 0; i < 8; ++i) {
                acc[i].x += a_[i] * b.x; acc[i].y += a_[i] * b.y;
                acc[i].z += a_[i] * b.z; acc[i].w += a_[i] * b.w;
            }
        }
        __syncthreads();
    }
#pragma unroll
    for (int i = 0; i < 8; ++i) {
        int m = m0 + tm * 8 + i;
        *(float4*)&C[(size_t)m * N + n0 + tn * 4] = acc[i];
    }
}

// --------------- depthwise causal conv (K=4) + bias + SiLU ------------------
__global__ __launch_bounds__(256)
void conv_silu_k(const float* __restrict__ proj, const float* __restrict__ cw,
                 const float* __restrict__ cb, float* __restrict__ convout)
{
    int idx = blockIdx.x * 256 + threadIdx.x;
    int d = idx % kConv, t = idx / kConv;
    float acc = cb[d];
#pragma unroll
    for (int k = 0; k < 4; ++k) {
        int ts = t + k - 3;
        float u = (ts >= 0) ? proj[(size_t)ts * kProj + kI + d] : 0.f;
        acc += u * cw[d * 4 + k];
    }
    convout[idx] = siluf(acc);
}

// --------------- dt = softplus(dt_raw + bias); per-chunk cumsum(dt*A) -------
__global__ __launch_bounds__(256)
void dt_cumsum_k(const float* __restrict__ proj, const float* __restrict__ dt_bias,
                 const float* __restrict__ A_log, float* __restrict__ dt,
                 float* __restrict__ acum)
{
    __shared__ float wsum[4];
    const int c = blockIdx.x >> 6, h = blockIdx.x & 63;
    const int l = threadIdx.x, t = c * kChunk + l;
    float a = -expf(A_log[h]);
    float z = proj[(size_t)t * kProj + kI + kConv + h] + dt_bias[h];
    float d = (z > 20.f) ? z : log1pf(expf(z));
    dt[t * kH + h] = d;
    float v = d * a;
    int lane = l & 63, w = l >> 6;
#pragma unroll
    for (int off = 1; off < 64; off <<= 1) {
        float u = __shfl_up(v, off);
        if (lane >= off) v += u;
    }
    if (lane == 63) wsum[w] = v;
    __syncthreads();
    float add = 0.f;
    for (int i = 0; i < w; ++i) add += wsum[i];
    acum[t * kH + h] = v + add;
}

// --------------- per-chunk end states ---------------------------------------
__global__ __launch_bounds__(256)
void states_k(const float* __restrict__ conv, const float* __restrict__ dt,
              const float* __restrict__ acum, float* __restrict__ states)
{
    __shared__ float Bl[64][132];
    __shared__ float Xl[64][68];
    __shared__ float Wl[64];
    const int c = blockIdx.x >> 6, h = blockIdx.x & 63;
    const int tid = threadIdx.x;
    const int p = tid & 63, ng = tid >> 6;
    const float aend = acum[(size_t)(c * kChunk + 255) * kH + h];
    float4 acc[8];
#pragma unroll
    for (int i = 0; i < 8; ++i) acc[i] = make_float4(0.f, 0.f, 0.f, 0.f);

    for (int lt = 0; lt < 4; ++lt) {
        int tbase = c * kChunk + lt * 64;
#pragma unroll
        for (int r = 0; r < 8; ++r) {
            int f = tid + 256 * r;
            int ll = f >> 5, c4 = (f & 31) * 4;
            *(float4*)&Bl[ll][c4] =
                *(const float4*)&conv[(size_t)(tbase + ll) * kConv + kI + c4];
        }
#pragma unroll
        for (int r = 0; r < 4; ++r) {
            int f = tid + 256 * r;
            int ll = f >> 4, c4 = (f & 15) * 4;
            *(float4*)&Xl[ll][c4] =
                *(const float4*)&conv[(size_t)(tbase + ll) * kConv + h * kP + c4];
        }
        if (tid < 64) {
            int t = tbase + tid;
            Wl[tid] = __expf(aend - acum[(size_t)t * kH + h]) * dt[(size_t)t * kH + h];
        }
        __syncthreads();
        for (int ll = 0; ll < 64; ++ll) {
            float xv = Xl[ll][p] * Wl[ll];
#pragma unroll
            for (int j = 0; j < 8; ++j) {
                float4 b = *(const float4*)&Bl[ll][ng * 32 + j * 4];
                acc[j] = f4fma(xv, b, acc[j]);
            }
        }
        __syncthreads();
    }
    size_t base = ((size_t)(c * kH + h) * kP + p) * kN + ng * 32;
#pragma unroll
    for (int j = 0; j < 8; ++j) *(float4*)&states[base + j * 4] = acc[j];
}

// --------------- sequential inter-chunk recurrence (8 chunks) ---------------
__global__ __launch_bounds__(256)
void scan_k(const float* __restrict__ states, const float* __restrict__ acum,
            float* __restrict__ prev)
{
    const int h = blockIdx.x >> 3, seg = blockIdx.x & 7;
    const int e = (seg * 256 + threadIdx.x) * 4;
    float4 carry = make_float4(0.f, 0.f, 0.f, 0.f);
    for (int c = 0; c < kNC; ++c) {
        size_t base = (size_t)(c * kH + h) * (kP * kN);
        *(float4*)&prev[base + e] = carry;
        float dec = __expf(acum[(size_t)(c * kChunk + 255) * kH + h]);
        float4 st = *(const float4*)&states[base + e];
        carry.x = carry.x * dec + st.x; carry.y = carry.y * dec + st.y;
        carry.z = carry.z * dec + st.z; carry.w = carry.w * dec + st.w;
    }
}

// --------------- SSD Y (v2): flash-style, reg-blocked 4x4, no spills --------
// block = (c, h, ti): 64 t-rows x 64 p-cols of Y. 256 thr: tm=tid>>4, tn=tid&15.
// acc[r][j]: t = ti*64+tm*4+r, p = tn*4+j.
// S-GEMM in K-slices of 32 via transposed LDS [k][row] (f4 reads, 2-way free).
// W round-trips LDS as Ws[s][t]; Y += W.X reads 2x b128 per 16 FMA.
// LDS = 53 KB -> 3 blocks/CU.
__global__ __launch_bounds__(256)
void ssd_y2_k(const float* __restrict__ conv, const float* __restrict__ dt,
              const float* __restrict__ acum, const float* __restrict__ prev,
              const float* __restrict__ Dp, float* __restrict__ Y)
{
    __shared__ float Cs[32][68];   // [k][t]  C k-slice, transposed
    __shared__ float Bs[32][68];   // [k][s]  B k-slice (also holds prev [n][p])
    __shared__ float Xs[64][68];   // [s][p]
    __shared__ float Ws[64][68];   // [s][t]
    __shared__ float At[64];       // Acum for t-rows
    __shared__ float Asv[64];      // Acum for s-rows of current si
    __shared__ float Dtv[64];      // dt  for s-rows of current si

    const int bi = blockIdx.x;
    const int ti = bi & 3, h = (bi >> 2) & 63, c = bi >> 8;
    const int tid = threadIdx.x;
    const int tm = tid >> 4, tn = tid & 15;
    const int trow0 = c * kChunk + ti * 64;       // global row of t-tile start

    if (tid < 64) At[tid] = acum[(size_t)(trow0 + tid) * kH + h];

    float acc[4][4];
#pragma unroll
    for (int r = 0; r < 4; ++r)
#pragma unroll
        for (int j = 0; j < 4; ++j) acc[r][j] = 0.f;

    // ---- inter-chunk: acc[t][p] = sum_n C[t][n] * prev[p][n] ----
    const size_t pbase = (size_t)(c * kH + h) * (kP * kN);
    for (int nt = 0; nt < 4; ++nt) {
#pragma unroll
        for (int i = 0; i < 2; ++i) {   // C slice: 64t x 32k, transpose-stage
            int f = tid + 256 * i;
            int row = f >> 3, kq = (f & 7) * 4;
            float4 v = *(const float4*)&conv[(size_t)(trow0 + row) * kConv +
                                             kI + kN + nt * 32 + kq];
            Cs[kq + 0][row] = v.x; Cs[kq + 1][row] = v.y;
            Cs[kq + 2][row] = v.z; Cs[kq + 3][row] = v.w;
        }
#pragma unroll
        for (int i = 0; i < 2; ++i) {   // prev slice: 64p x 32n -> Bs[n][p]
            int f = tid + 256 * i;
            int p = f >> 3, kq = (f & 7) * 4;
            float4 v = *(const float4*)&prev[pbase + (size_t)p * kN + nt * 32 + kq];
            Bs[kq + 0][p] = v.x; Bs[kq + 1][p] = v.y;
            Bs[kq + 2][p] = v.z; Bs[kq + 3][p] = v.w;
        }
        __syncthreads();
#pragma unroll
        for (int k = 0; k < 32; ++k) {
            float4 cv = *(const float4*)&Cs[k][tm * 4];
            float4 pv = *(const float4*)&Bs[k][tn * 4];
            float c_[4] = {cv.x, cv.y, cv.z, cv.w};
#pragma unroll
            for (int r = 0; r < 4; ++r) {
                acc[r][0] += c_[r] * pv.x; acc[r][1] += c_[r] * pv.y;
                acc[r][2] += c_[r] * pv.z; acc[r][3] += c_[r] * pv.w;
            }
        }
        __syncthreads();
    }

    // ---- scale by exp(Acum_t), add D skip ----
    const float Dh = Dp[h];
#pragma unroll
    for (int r = 0; r < 4; ++r) {
        float eA = __expf(At[tm * 4 + r]);
        float4 x4 = *(const float4*)&conv[(size_t)(trow0 + tm * 4 + r) * kConv +
                                          h * kP + tn * 4];
        acc[r][0] = acc[r][0] * eA + Dh * x4.x;
        acc[r][1] = acc[r][1] * eA + Dh * x4.y;
        acc[r][2] = acc[r][2] * eA + Dh * x4.z;
        acc[r][3] = acc[r][3] * eA + Dh * x4.w;
    }

    // ---- intra-chunk causal: si = 0..ti ----
    for (int si = 0; si <= ti; ++si) {
        const int srow0 = c * kChunk + si * 64;
#pragma unroll
        for (int i = 0; i < 4; ++i) {   // X tile: 64s x 64p
            int f = tid + 256 * i;
            int row = f >> 4, pq = (f & 15) * 4;
            *(float4*)&Xs[row][pq] =
                *(const float4*)&conv[(size_t)(srow0 + row) * kConv + h * kP + pq];
        }
        if (tid < 64) {
            Asv[tid] = acum[(size_t)(srow0 + tid) * kH + h];
            Dtv[tid] = dt[(size_t)(srow0 + tid) * kH + h];
        }
        float sreg[4][4];
#pragma unroll
        for (int r = 0; r < 4; ++r)
#pragma unroll
            for (int j = 0; j < 4; ++j) sreg[r][j] = 0.f;

        for (int nt = 0; nt < 4; ++nt) {
#pragma unroll
            for (int i = 0; i < 2; ++i) {   // C slice (transpose)
                int f = tid + 256 * i;
                int row = f >> 3, kq = (f & 7) * 4;
                float4 v = *(const float4*)&conv[(size_t)(trow0 + row) * kConv +
                                                 kI + kN + nt * 32 + kq];
                Cs[kq + 0][row] = v.x; Cs[kq + 1][row] = v.y;
                Cs[kq + 2][row] = v.z; Cs[kq + 3][row] = v.w;
            }
#pragma unroll
            for (int i = 0; i < 2; ++i) {   // B slice (transpose)
                int f = tid + 256 * i;
                int row = f >> 3, kq = (f & 7) * 4;
                float4 v = *(const float4*)&conv[(size_t)(srow0 + row) * kConv +
                                                 kI + nt * 32 + kq];
                Bs[kq + 0][row] = v.x; Bs[kq + 1][row] = v.y;
                Bs[kq + 2][row] = v.z; Bs[kq + 3][row] = v.w;
            }
            __syncthreads();
#pragma unroll
            for (int k = 0; k < 32; ++k) {
                float4 cv = *(const float4*)&Cs[k][tm * 4];
                float4 bv = *(const float4*)&Bs[k][tn * 4];
                float c_[4] = {cv.x, cv.y, cv.z, cv.w};
#pragma unroll
                for (int r = 0; r < 4; ++r) {
                    sreg[r][0] += c_[r] * bv.x; sreg[r][1] += c_[r] * bv.y;
                    sreg[r][2] += c_[r] * bv.z; sreg[r][3] += c_[r] * bv.w;
                }
            }
            __syncthreads();
        }

        // weight + mask, write Ws[s][t]
        const bool diag = (si == ti);
#pragma unroll
        for (int r = 0; r < 4; ++r) {
            int tl = tm * 4 + r;
            float at = At[tl];
#pragma unroll
            for (int j = 0; j < 4; ++j) {
                int sl = tn * 4 + j;
                float w = sreg[r][j] * __expf(at - Asv[sl]) * Dtv[sl];
                if (diag && sl > tl) w = 0.f;
                Ws[sl][tl] = w;
            }
        }
        __syncthreads();
        // Y += W . X over s=64
#pragma unroll 8
        for (int s = 0; s < 64; ++s) {
            float4 wv = *(const float4*)&Ws[s][tm * 4];
            float4 xv = *(const float4*)&Xs[s][tn * 4];
            float w_[4] = {wv.x, wv.y, wv.z, wv.w};
#pragma unroll
            for (int r = 0; r < 4; ++r) {
                acc[r][0] += w_[r] * xv.x; acc[r][1] += w_[r] * xv.y;
                acc[r][2] += w_[r] * xv.z; acc[r][3] += w_[r] * xv.w;
            }
        }
        __syncthreads();
    }

#pragma unroll
    for (int r = 0; r < 4; ++r) {
        float4 o = make_float4(acc[r][0], acc[r][1], acc[r][2], acc[r][3]);
        *(float4*)&Y[(size_t)(trow0 + tm * 4 + r) * kI + h * kP + tn * 4] = o;
    }
}

// --------------- gated RMSNorm (gate before norm), in-place on Y ------------
__global__ __launch_bounds__(256)
void rmsnorm_gate_k(float* __restrict__ Y, const float* __restrict__ proj,
                    const float* __restrict__ nw)
{
    __shared__ float red[4];
    const int t = blockIdx.x, tid = threadIdx.x;
    float* yrow = &Y[(size_t)t * kI];
    const float* grow = &proj[(size_t)t * kProj];
    float v[16];
    float ss = 0.f;
#pragma unroll
    for (int j = 0; j < 4; ++j) {
        int i = (tid + 256 * j) * 4;
        float4 y4 = *(const float4*)&yrow[i];
        float4 g4 = *(const float4*)&grow[i];
        float a = y4.x * siluf(g4.x), bq = y4.y * siluf(g4.y);
        float cq = y4.z * siluf(g4.z), d = y4.w * siluf(g4.w);
        v[j * 4 + 0] = a; v[j * 4 + 1] = bq; v[j * 4 + 2] = cq; v[j * 4 + 3] = d;
        ss += a * a + bq * bq + cq * cq + d * d;
    }
#pragma unroll
    for (int off = 32; off > 0; off >>= 1) ss += __shfl_down(ss, off);
    if ((tid & 63) == 0) red[tid >> 6] = ss;
    __syncthreads();
    float sum = red[0] + red[1] + red[2] + red[3];
    float rr = rsqrtf(sum * (1.f / kI) + kEps);
#pragma unroll
    for (int j = 0; j < 4; ++j) {
        int i = (tid + 256 * j) * 4;
        float4 w4 = *(const float4*)&nw[i];
        float4 o;
        o.x = v[j * 4 + 0] * rr * w4.x; o.y = v[j * 4 + 1] * rr * w4.y;
        o.z = v[j * 4 + 2] * rr * w4.z; o.w = v[j * 4 + 3] * rr * w4.w;
        *(float4*)&yrow[i] = o;
    }
}

extern "C" void kernel_launch(void* const* d_in, const int* in_sizes, int n_in,
                              void* d_out, int out_size, void* d_ws, size_t ws_size,
                              hipStream_t stream)
{
    const float* x       = (const float*)d_in[0];
    const float* W_in    = (const float*)d_in[1];
    const float* conv_w  = (const float*)d_in[2];
    const float* conv_b  = (const float*)d_in[3];
    const float* dt_bias = (const float*)d_in[4];
    const float* A_log   = (const float*)d_in[5];
    const float* Dp      = (const float*)d_in[6];
    const float* norm_w  = (const float*)d_in[7];
    const float* W_out   = (const float*)d_in[8];
    float* out = (float*)d_out;

    float* ws     = (float*)d_ws;
    float* proj   = ws;                                   // kS*kProj
    float* conv   = proj + (size_t)kS * kProj;            // kS*kConv
    float* dtb    = conv + (size_t)kS * kConv;            // kS*kH
    float* acum   = dtb + (size_t)kS * kH;                // kS*kH
    float* prev   = acum + (size_t)kS * kH;               // kNC*kH*kP*kN
    float* Y      = prev + (size_t)kNC * kH * kP * kN;    // kS*kI
    float* states = Y;                                    // alias

    dim3 blk(256);
    gemm_nt_f32<<<dim3(kProj / 64, kS / 128), blk, 0, stream>>>(x, W_in, proj, kS, kProj, kHID);
    conv_silu_k<<<(kS * kConv) / 256, blk, 0, stream>>>(proj, conv_w, conv_b, conv);
    dt_cumsum_k<<<kNC * kH, blk, 0, stream>>>(proj, dt_bias, A_log, dtb, acum);
    states_k<<<kNC * kH, blk, 0, stream>>>(conv, dtb, acum, states);
    scan_k<<<kH * 8, blk, 0, stream>>>(states, acum, prev);
    ssd_y2_k<<<kNC * kH * 4, blk, 0, stream>>>(conv, dtb, acum, prev, Dp, Y);
    rmsnorm_gate_k<<<kS, blk, 0, stream>>>(Y, proj, norm_w);
    gemm_nt_f32<<<dim3(kHID / 64, kS / 128), blk, 0, stream>>>(Y, W_out, out, kS, kHID, kI);
}

// Round 3
// 825.141 us; speedup vs baseline: 4.1904x; 2.3300x over previous
//
#include <hip/hip_runtime.h>
#include <math.h>

// Bamba-9B mixer, b=1 s=2048. Round 2: big GEMMs -> bf16 MFMA (m97 structure).
// dt path kept fp32 (errors amplified by A up to -64 in cumsum exponentials).
static constexpr int kS     = 2048;
static constexpr int kHID   = 2048;
static constexpr int kI     = 4096;
static constexpr int kH     = 64;
static constexpr int kP     = 64;
static constexpr int kN     = 128;
static constexpr int kConv  = 4352;   // I + 2*G*N
static constexpr int kProjC = 8448;   // I + CONV  (gate + conv cols only; dt separate)
static constexpr int kChunk = 256;
static constexpr int kNC    = 8;
static constexpr float kEps = 1e-5f;

typedef __attribute__((ext_vector_type(8))) short short8;    // 8 x bf16 fragment
typedef __attribute__((ext_vector_type(4))) float floatx4;   // MFMA accumulator

__device__ __forceinline__ float4 f4fma(float a, float4 b, float4 c) {
    c.x += a * b.x; c.y += a * b.y; c.z += a * b.z; c.w += a * b.w; return c;
}
__device__ __forceinline__ float siluf(float x) {
    return x / (1.f + __expf(-x));
}
__device__ __forceinline__ unsigned short f2bf(float f) {   // RNE, finite inputs
    unsigned int u = __float_as_uint(f);
    return (unsigned short)((u + 0x7FFFu + ((u >> 16) & 1u)) >> 16);
}
__device__ __forceinline__ void gll16(const void* g, void* l) {
    __builtin_amdgcn_global_load_lds(
        (const __attribute__((address_space(1))) void*)g,
        (__attribute__((address_space(3))) void*)l, 16, 0, 0);
}

// ---------- fp32 -> bf16 cast, 8 elems/thread ----------
__global__ __launch_bounds__(256)
void cast_bf16_k(const float* __restrict__ in, unsigned short* __restrict__ out)
{
    size_t i = ((size_t)blockIdx.x * 256 + threadIdx.x) * 8;
    float4 a = *(const float4*)&in[i];
    float4 b = *(const float4*)&in[i + 4];
    ushort4 u0 = {f2bf(a.x), f2bf(a.y), f2bf(a.z), f2bf(a.w)};
    ushort4 u1 = {f2bf(b.x), f2bf(b.y), f2bf(b.z), f2bf(b.w)};
    *(ushort4*)&out[i] = u0;
    *(ushort4*)&out[i + 4] = u1;
}

// ---------- bf16 MFMA NT GEMM: C[M,N] = A[M,K] * B[N,K]^T ----------
// 256 thr = 4 waves, tile 128x128, BK=32, mfma_f32_16x16x32_bf16.
// LDS tiles [row][k] 128x32 bf16, staged via global_load_lds width 16
// (lane-contiguous: segment f = tid+256*i -> LDS byte f*16, row=f>>2, k8=(f&3)*8).
// Frags: A[m=lane&15][k=quad*8+j]; C/D: col=lane&15, row=quad*4+reg (m89/m91).
__global__ __launch_bounds__(256)
void gemm_bt_bf16(const unsigned short* __restrict__ A,
                  const unsigned short* __restrict__ B,
                  float* __restrict__ C, int M, int N, int K)
{
    __shared__ unsigned short As[128 * 32];
    __shared__ unsigned short Bs[128 * 32];
    const int tid = threadIdx.x;
    const int lane = tid & 63, quad = lane >> 4, l15 = lane & 15;
    const int wave = tid >> 6;
    const int m0 = blockIdx.y * 128, n0 = blockIdx.x * 128;
    const int wm = (wave & 1) * 64, wn = (wave >> 1) * 64;

    floatx4 acc[4][4] = {};

    const int r0 = tid >> 2, k8a = (tid & 3) * 8;          // staging coords, i=0
    const int r1 = (tid + 256) >> 2, k8b = (tid & 3) * 8;  // i=1 (same k8)

    for (int k0 = 0; k0 < K; k0 += 32) {
        gll16(&A[(size_t)(m0 + r0) * K + k0 + k8a], &As[(size_t)tid * 8]);
        gll16(&A[(size_t)(m0 + r1) * K + k0 + k8b], &As[(size_t)(tid + 256) * 8]);
        gll16(&B[(size_t)(n0 + r0) * K + k0 + k8a], &Bs[(size_t)tid * 8]);
        gll16(&B[(size_t)(n0 + r1) * K + k0 + k8b], &Bs[(size_t)(tid + 256) * 8]);
        __syncthreads();   // drains vmcnt (compiler emits waitcnt before barrier)

        short8 af[4], bf[4];
#pragma unroll
        for (int mi = 0; mi < 4; ++mi)
            af[mi] = *(const short8*)&As[(size_t)(wm + mi * 16 + l15) * 32 + quad * 8];
#pragma unroll
        for (int ni = 0; ni < 4; ++ni)
            bf[ni] = *(const short8*)&Bs[(size_t)(wn + ni * 16 + l15) * 32 + quad * 8];
#pragma unroll
        for (int mi = 0; mi < 4; ++mi)
#pragma unroll
            for (int ni = 0; ni < 4; ++ni)
                acc[mi][ni] = __builtin_amdgcn_mfma_f32_16x16x32_bf16(
                    af[mi], bf[ni], acc[mi][ni], 0, 0, 0);
        __syncthreads();   // protect LDS from next iteration's staging
    }

#pragma unroll
    for (int mi = 0; mi < 4; ++mi)
#pragma unroll
        for (int ni = 0; ni < 4; ++ni) {
            int col = n0 + wn + ni * 16 + l15;
#pragma unroll
            for (int r = 0; r < 4; ++r) {
                int row = m0 + wm + mi * 16 + quad * 4 + r;
                C[(size_t)row * N + col] = acc[mi][ni][r];
            }
        }
}

// --------------- depthwise causal conv (K=4) + bias + SiLU ------------------
__global__ __launch_bounds__(256)
void conv_silu_k(const float* __restrict__ proj, const float* __restrict__ cw,
                 const float* __restrict__ cb, float* __restrict__ convout)
{
    int idx = blockIdx.x * 256 + threadIdx.x;
    int d = idx % kConv, t = idx / kConv;
    float acc = cb[d];
#pragma unroll
    for (int k = 0; k < 4; ++k) {
        int ts = t + k - 3;
        float u = (ts >= 0) ? proj[(size_t)ts * kProjC + kI + d] : 0.f;
        acc += u * cw[d * 4 + k];
    }
    convout[idx] = siluf(acc);
}

// --------------- dt_raw fp32 dot + softplus + per-chunk cumsum --------------
// block = (chunk, head); W_in dt-row staged in LDS; thread t: dot(x[t,:], wrow).
__global__ __launch_bounds__(256)
void dt_cumsum_k(const float* __restrict__ x, const float* __restrict__ W_in,
                 const float* __restrict__ dt_bias, const float* __restrict__ A_log,
                 float* __restrict__ dt, float* __restrict__ acum)
{
    __shared__ float wrow[kHID];
    __shared__ float wsum[4];
    const int c = blockIdx.x >> 6, h = blockIdx.x & 63;
    const int l = threadIdx.x, t = c * kChunk + l;

    const float4* wr = (const float4*)&W_in[(size_t)(kI + kConv + h) * kHID];
#pragma unroll
    for (int i = 0; i < 2; ++i) ((float4*)wrow)[l + 256 * i] = wr[l + 256 * i];
    __syncthreads();

    const float4* xr = (const float4*)&x[(size_t)t * kHID];
    float4 s4 = make_float4(0.f, 0.f, 0.f, 0.f);
#pragma unroll 8
    for (int i = 0; i < kHID / 4; ++i) {
        float4 xv = xr[i];
        float4 wv = ((const float4*)wrow)[i];
        s4.x += xv.x * wv.x; s4.y += xv.y * wv.y;
        s4.z += xv.z * wv.z; s4.w += xv.w * wv.w;
    }
    float z = s4.x + s4.y + s4.z + s4.w + dt_bias[h];

    float a = -expf(A_log[h]);
    float d = (z > 20.f) ? z : log1pf(expf(z));
    dt[t * kH + h] = d;
    float v = d * a;
    int lane = l & 63, w = l >> 6;
#pragma unroll
    for (int off = 1; off < 64; off <<= 1) {
        float u = __shfl_up(v, off);
        if (lane >= off) v += u;
    }
    if (lane == 63) wsum[w] = v;
    __syncthreads();
    float add = 0.f;
    for (int i = 0; i < w; ++i) add += wsum[i];
    acum[t * kH + h] = v + add;
}

// --------------- per-chunk end states ---------------------------------------
__global__ __launch_bounds__(256)
void states_k(const float* __restrict__ conv, const float* __restrict__ dt,
              const float* __restrict__ acum, float* __restrict__ states)
{
    __shared__ float Bl[64][132];
    __shared__ float Xl[64][68];
    __shared__ float Wl[64];
    const int c = blockIdx.x >> 6, h = blockIdx.x & 63;
    const int tid = threadIdx.x;
    const int p = tid & 63, ng = tid >> 6;
    const float aend = acum[(size_t)(c * kChunk + 255) * kH + h];
    float4 acc[8];
#pragma unroll
    for (int i = 0; i < 8; ++i) acc[i] = make_float4(0.f, 0.f, 0.f, 0.f);

    for (int lt = 0; lt < 4; ++lt) {
        int tbase = c * kChunk + lt * 64;
#pragma unroll
        for (int r = 0; r < 8; ++r) {
            int f = tid + 256 * r;
            int ll = f >> 5, c4 = (f & 31) * 4;
            *(float4*)&Bl[ll][c4] =
                *(const float4*)&conv[(size_t)(tbase + ll) * kConv + kI + c4];
        }
#pragma unroll
        for (int r = 0; r < 4; ++r) {
            int f = tid + 256 * r;
            int ll = f >> 4, c4 = (f & 15) * 4;
            *(float4*)&Xl[ll][c4] =
                *(const float4*)&conv[(size_t)(tbase + ll) * kConv + h * kP + c4];
        }
        if (tid < 64) {
            int t = tbase + tid;
            Wl[tid] = __expf(aend - acum[(size_t)t * kH + h]) * dt[(size_t)t * kH + h];
        }
        __syncthreads();
        for (int ll = 0; ll < 64; ++ll) {
            float xv = Xl[ll][p] * Wl[ll];
#pragma unroll
            for (int j = 0; j < 8; ++j) {
                float4 b = *(const float4*)&Bl[ll][ng * 32 + j * 4];
                acc[j] = f4fma(xv, b, acc[j]);
            }
        }
        __syncthreads();
    }
    size_t base = ((size_t)(c * kH + h) * kP + p) * kN + ng * 32;
#pragma unroll
    for (int j = 0; j < 8; ++j) *(float4*)&states[base + j * 4] = acc[j];
}

// --------------- sequential inter-chunk recurrence (8 chunks) ---------------
__global__ __launch_bounds__(256)
void scan_k(const float* __restrict__ states, const float* __restrict__ acum,
            float* __restrict__ prev)
{
    const int h = blockIdx.x >> 3, seg = blockIdx.x & 7;
    const int e = (seg * 256 + threadIdx.x) * 4;
    float4 carry = make_float4(0.f, 0.f, 0.f, 0.f);
    for (int c = 0; c < kNC; ++c) {
        size_t base = (size_t)(c * kH + h) * (kP * kN);
        *(float4*)&prev[base + e] = carry;
        float dec = __expf(acum[(size_t)(c * kChunk + 255) * kH + h]);
        float4 st = *(const float4*)&states[base + e];
        carry.x = carry.x * dec + st.x; carry.y = carry.y * dec + st.y;
        carry.z = carry.z * dec + st.z; carry.w = carry.w * dec + st.w;
    }
}

// --------------- SSD Y: flash-style, reg-blocked 4x4 ------------------------
__global__ __launch_bounds__(256)
void ssd_y2_k(const float* __restrict__ conv, const float* __restrict__ dt,
              const float* __restrict__ acum, const float* __restrict__ prev,
              const float* __restrict__ Dp, float* __restrict__ Y)
{
    __shared__ float Cs[32][68];
    __shared__ float Bs[32][68];
    __shared__ float Xs[64][68];
    __shared__ float Ws[64][68];
    __shared__ float At[64];
    __shared__ float Asv[64];
    __shared__ float Dtv[64];

    const int bi = blockIdx.x;
    const int ti = bi & 3, h = (bi >> 2) & 63, c = bi >> 8;
    const int tid = threadIdx.x;
    const int tm = tid >> 4, tn = tid & 15;
    const int trow0 = c * kChunk + ti * 64;

    if (tid < 64) At[tid] = acum[(size_t)(trow0 + tid) * kH + h];

    float acc[4][4];
#pragma unroll
    for (int r = 0; r < 4; ++r)
#pragma unroll
        for (int j = 0; j < 4; ++j) acc[r][j] = 0.f;

    const size_t pbase = (size_t)(c * kH + h) * (kP * kN);
    for (int nt = 0; nt < 4; ++nt) {
#pragma unroll
        for (int i = 0; i < 2; ++i) {
            int f = tid + 256 * i;
            int row = f >> 3, kq = (f & 7) * 4;
            float4 v = *(const float4*)&conv[(size_t)(trow0 + row) * kConv +
                                             kI + kN + nt * 32 + kq];
            Cs[kq + 0][row] = v.x; Cs[kq + 1][row] = v.y;
            Cs[kq + 2][row] = v.z; Cs[kq + 3][row] = v.w;
        }
#pragma unroll
        for (int i = 0; i < 2; ++i) {
            int f = tid + 256 * i;
            int p = f >> 3, kq = (f & 7) * 4;
            float4 v = *(const float4*)&prev[pbase + (size_t)p * kN + nt * 32 + kq];
            Bs[kq + 0][p] = v.x; Bs[kq + 1][p] = v.y;
            Bs[kq + 2][p] = v.z; Bs[kq + 3][p] = v.w;
        }
        __syncthreads();
#pragma unroll
        for (int k = 0; k < 32; ++k) {
            float4 cv = *(const float4*)&Cs[k][tm * 4];
            float4 pv = *(const float4*)&Bs[k][tn * 4];
            float c_[4] = {cv.x, cv.y, cv.z, cv.w};
#pragma unroll
            for (int r = 0; r < 4; ++r) {
                acc[r][0] += c_[r] * pv.x; acc[r][1] += c_[r] * pv.y;
                acc[r][2] += c_[r] * pv.z; acc[r][3] += c_[r] * pv.w;
            }
        }
        __syncthreads();
    }

    const float Dh = Dp[h];
#pragma unroll
    for (int r = 0; r < 4; ++r) {
        float eA = __expf(At[tm * 4 + r]);
        float4 x4 = *(const float4*)&conv[(size_t)(trow0 + tm * 4 + r) * kConv +
                                          h * kP + tn * 4];
        acc[r][0] = acc[r][0] * eA + Dh * x4.x;
        acc[r][1] = acc[r][1] * eA + Dh * x4.y;
        acc[r][2] = acc[r][2] * eA + Dh * x4.z;
        acc[r][3] = acc[r][3] * eA + Dh * x4.w;
    }

    for (int si = 0; si <= ti; ++si) {
        const int srow0 = c * kChunk + si * 64;
#pragma unroll
        for (int i = 0; i < 4; ++i) {
            int f = tid + 256 * i;
            int row = f >> 4, pq = (f & 15) * 4;
            *(float4*)&Xs[row][pq] =
                *(const float4*)&conv[(size_t)(srow0 + row) * kConv + h * kP + pq];
        }
        if (tid < 64) {
            Asv[tid] = acum[(size_t)(srow0 + tid) * kH + h];
            Dtv[tid] = dt[(size_t)(srow0 + tid) * kH + h];
        }
        float sreg[4][4];
#pragma unroll
        for (int r = 0; r < 4; ++r)
#pragma unroll
            for (int j = 0; j < 4; ++j) sreg[r][j] = 0.f;

        for (int nt = 0; nt < 4; ++nt) {
#pragma unroll
            for (int i = 0; i < 2; ++i) {
                int f = tid + 256 * i;
                int row = f >> 3, kq = (f & 7) * 4;
                float4 v = *(const float4*)&conv[(size_t)(trow0 + row) * kConv +
                                                 kI + kN + nt * 32 + kq];
                Cs[kq + 0][row] = v.x; Cs[kq + 1][row] = v.y;
                Cs[kq + 2][row] = v.z; Cs[kq + 3][row] = v.w;
            }
#pragma unroll
            for (int i = 0; i < 2; ++i) {
                int f = tid + 256 * i;
                int row = f >> 3, kq = (f & 7) * 4;
                float4 v = *(const float4*)&conv[(size_t)(srow0 + row) * kConv +
                                                 kI + nt * 32 + kq];
                Bs[kq + 0][row] = v.x; Bs[kq + 1][row] = v.y;
                Bs[kq + 2][row] = v.z; Bs[kq + 3][row] = v.w;
            }
            __syncthreads();
#pragma unroll
            for (int k = 0; k < 32; ++k) {
                float4 cv = *(const float4*)&Cs[k][tm * 4];
                float4 bv = *(const float4*)&Bs[k][tn * 4];
                float c_[4] = {cv.x, cv.y, cv.z, cv.w};
#pragma unroll
                for (int r = 0; r < 4; ++r) {
                    sreg[r][0] += c_[r] * bv.x; sreg[r][1] += c_[r] * bv.y;
                    sreg[r][2] += c_[r] * bv.z; sreg[r][3] += c_[r] * bv.w;
                }
            }
            __syncthreads();
        }

        const bool diag = (si == ti);
#pragma unroll
        for (int r = 0; r < 4; ++r) {
            int tl = tm * 4 + r;
            float at = At[tl];
#pragma unroll
            for (int j = 0; j < 4; ++j) {
                int sl = tn * 4 + j;
                float w = sreg[r][j] * __expf(at - Asv[sl]) * Dtv[sl];
                if (diag && sl > tl) w = 0.f;
                Ws[sl][tl] = w;
            }
        }
        __syncthreads();
#pragma unroll 8
        for (int s = 0; s < 64; ++s) {
            float4 wv = *(const float4*)&Ws[s][tm * 4];
            float4 xv = *(const float4*)&Xs[s][tn * 4];
            float w_[4] = {wv.x, wv.y, wv.z, wv.w};
#pragma unroll
            for (int r = 0; r < 4; ++r) {
                acc[r][0] += w_[r] * xv.x; acc[r][1] += w_[r] * xv.y;
                acc[r][2] += w_[r] * xv.z; acc[r][3] += w_[r] * xv.w;
            }
        }
        __syncthreads();
    }

#pragma unroll
    for (int r = 0; r < 4; ++r) {
        float4 o = make_float4(acc[r][0], acc[r][1], acc[r][2], acc[r][3]);
        *(float4*)&Y[(size_t)(trow0 + tm * 4 + r) * kI + h * kP + tn * 4] = o;
    }
}

// --------------- gated RMSNorm -> bf16 output for final MFMA GEMM -----------
__global__ __launch_bounds__(256)
void rmsnorm_gate_k(const float* __restrict__ Y, const float* __restrict__ proj,
                    const float* __restrict__ nw, unsigned short* __restrict__ Yb)
{
    __shared__ float red[4];
    const int t = blockIdx.x, tid = threadIdx.x;
    const float* yrow = &Y[(size_t)t * kI];
    const float* grow = &proj[(size_t)t * kProjC];
    float v[16];
    float ss = 0.f;
#pragma unroll
    for (int j = 0; j < 4; ++j) {
        int i = (tid + 256 * j) * 4;
        float4 y4 = *(const float4*)&yrow[i];
        float4 g4 = *(const float4*)&grow[i];
        float a = y4.x * siluf(g4.x), bq = y4.y * siluf(g4.y);
        float cq = y4.z * siluf(g4.z), d = y4.w * siluf(g4.w);
        v[j * 4 + 0] = a; v[j * 4 + 1] = bq; v[j * 4 + 2] = cq; v[j * 4 + 3] = d;
        ss += a * a + bq * bq + cq * cq + d * d;
    }
#pragma unroll
    for (int off = 32; off > 0; off >>= 1) ss += __shfl_down(ss, off);
    if ((tid & 63) == 0) red[tid >> 6] = ss;
    __syncthreads();
    float sum = red[0] + red[1] + red[2] + red[3];
    float rr = rsqrtf(sum * (1.f / kI) + kEps);
#pragma unroll
    for (int j = 0; j < 4; ++j) {
        int i = (tid + 256 * j) * 4;
        float4 w4 = *(const float4*)&nw[i];
        ushort4 o;
        o.x = f2bf(v[j * 4 + 0] * rr * w4.x);
        o.y = f2bf(v[j * 4 + 1] * rr * w4.y);
        o.z = f2bf(v[j * 4 + 2] * rr * w4.z);
        o.w = f2bf(v[j * 4 + 3] * rr * w4.w);
        *(ushort4*)&Yb[(size_t)t * kI + i] = o;
    }
}

extern "C" void kernel_launch(void* const* d_in, const int* in_sizes, int n_in,
                              void* d_out, int out_size, void* d_ws, size_t ws_size,
                              hipStream_t stream)
{
    const float* x       = (const float*)d_in[0];
    const float* W_in    = (const float*)d_in[1];
    const float* conv_w  = (const float*)d_in[2];
    const float* conv_b  = (const float*)d_in[3];
    const float* dt_bias = (const float*)d_in[4];
    const float* A_log   = (const float*)d_in[5];
    const float* Dp      = (const float*)d_in[6];
    const float* norm_w  = (const float*)d_in[7];
    const float* W_out   = (const float*)d_in[8];
    float* out = (float*)d_out;

    // workspace (floats), 156.2 MB total, heavy aliasing (timeline in comments):
    // R1 region: Wb(cast->projGEMM) -> prev+Y/states -> Yb(after ssd_y2)
    // conv region: xb(before conv written) ... conv ... Wob(after ssd_y2)
    float* ws   = (float*)d_ws;
    float* proj = ws;                                    // 2048*8448
    float* conv = proj + (size_t)kS * kProjC;            // 2048*4352
    float* dtb  = conv + (size_t)kS * kConv;             // 2048*64
    float* acum = dtb + (size_t)kS * kH;                 // 2048*64
    float* R1   = acum + (size_t)kS * kH;                // 12,582,912 floats
    float* prev   = R1;                                  // 4,194,304
    float* Y      = R1 + (size_t)kNC * kH * kP * kN;     // 8,388,608
    float* states = Y;
    unsigned short* Wb  = (unsigned short*)R1;           // 8448*2048 bf16 (early)
    unsigned short* Yb  = (unsigned short*)R1;           // 2048*4096 bf16 (late)
    unsigned short* xb  = (unsigned short*)conv;         // 2048*2048 bf16 (early)
    unsigned short* Wob = (unsigned short*)conv;         // 2048*4096 bf16 (late)

    dim3 blk(256);
    cast_bf16_k<<<(kS * kHID) / 2048, blk, 0, stream>>>(x, xb);
    cast_bf16_k<<<(kProjC * kHID) / 2048, blk, 0, stream>>>(W_in, Wb);
    gemm_bt_bf16<<<dim3(kProjC / 128, kS / 128), blk, 0, stream>>>(
        xb, Wb, proj, kS, kProjC, kHID);
    conv_silu_k<<<(kS * kConv) / 256, blk, 0, stream>>>(proj, conv_w, conv_b, conv);
    dt_cumsum_k<<<kNC * kH, blk, 0, stream>>>(x, W_in, dt_bias, A_log, dtb, acum);
    states_k<<<kNC * kH, blk, 0, stream>>>(conv, dtb, acum, states);
    scan_k<<<kH * 8, blk, 0, stream>>>(states, acum, prev);
    ssd_y2_k<<<kNC * kH * 4, blk, 0, stream>>>(conv, dtb, acum, prev, Dp, Y);
    rmsnorm_gate_k<<<kS, blk, 0, stream>>>(Y, proj, norm_w, Yb);
    cast_bf16_k<<<(kHID * kI) / 2048, blk, 0, stream>>>(W_out, Wob);
    gemm_bt_bf16<<<dim3(kHID / 128, kS / 128), blk, 0, stream>>>(
        Yb, Wob, out, kS, kHID, kI);
}

// Round 4
// 645.616 us; speedup vs baseline: 5.3556x; 1.2781x over previous
//
#include <hip/hip_runtime.h>
#include <math.h>

// Bamba-9B mixer, b=1 s=2048. Round 3: SSD Y -> bf16 MFMA (all three products).
// dt/exp/cumsum kept fp32 (errors amplified by A up to -64 in exponentials).
static constexpr int kS     = 2048;
static constexpr int kHID   = 2048;
static constexpr int kI     = 4096;
static constexpr int kH     = 64;
static constexpr int kP     = 64;
static constexpr int kN     = 128;
static constexpr int kConv  = 4352;   // I + 2*G*N
static constexpr int kProjC = 8448;   // I + CONV  (gate + conv cols only; dt separate)
static constexpr int kChunk = 256;
static constexpr int kNC    = 8;
static constexpr float kEps = 1e-5f;

typedef __attribute__((ext_vector_type(8))) short short8;    // 8 x bf16 fragment
typedef __attribute__((ext_vector_type(4))) float floatx4;   // MFMA accumulator

__device__ __forceinline__ float4 f4fma(float a, float4 b, float4 c) {
    c.x += a * b.x; c.y += a * b.y; c.z += a * b.z; c.w += a * b.w; return c;
}
__device__ __forceinline__ float siluf(float x) {
    return x / (1.f + __expf(-x));
}
__device__ __forceinline__ unsigned short f2bf(float f) {   // RNE, finite inputs
    unsigned int u = __float_as_uint(f);
    return (unsigned short)((u + 0x7FFFu + ((u >> 16) & 1u)) >> 16);
}
__device__ __forceinline__ void gll16(const void* g, void* l) {
    __builtin_amdgcn_global_load_lds(
        (const __attribute__((address_space(1))) void*)g,
        (__attribute__((address_space(3))) void*)l, 16, 0, 0);
}

// ---------- fp32 -> bf16 cast, 8 elems/thread ----------
__global__ __launch_bounds__(256)
void cast_bf16_k(const float* __restrict__ in, unsigned short* __restrict__ out)
{
    size_t i = ((size_t)blockIdx.x * 256 + threadIdx.x) * 8;
    float4 a = *(const float4*)&in[i];
    float4 b = *(const float4*)&in[i + 4];
    ushort4 u0 = {f2bf(a.x), f2bf(a.y), f2bf(a.z), f2bf(a.w)};
    ushort4 u1 = {f2bf(b.x), f2bf(b.y), f2bf(b.z), f2bf(b.w)};
    *(ushort4*)&out[i] = u0;
    *(ushort4*)&out[i + 4] = u1;
}

// ---------- bf16 MFMA NT GEMM: C[M,N] = A[M,K] * B[N,K]^T ----------
__global__ __launch_bounds__(256)
void gemm_bt_bf16(const unsigned short* __restrict__ A,
                  const unsigned short* __restrict__ B,
                  float* __restrict__ C, int M, int N, int K)
{
    __shared__ unsigned short As[128 * 32];
    __shared__ unsigned short Bs[128 * 32];
    const int tid = threadIdx.x;
    const int lane = tid & 63, quad = lane >> 4, l15 = lane & 15;
    const int wave = tid >> 6;
    const int m0 = blockIdx.y * 128, n0 = blockIdx.x * 128;
    const int wm = (wave & 1) * 64, wn = (wave >> 1) * 64;

    floatx4 acc[4][4] = {};

    const int r0 = tid >> 2, k8a = (tid & 3) * 8;
    const int r1 = (tid + 256) >> 2, k8b = (tid & 3) * 8;

    for (int k0 = 0; k0 < K; k0 += 32) {
        gll16(&A[(size_t)(m0 + r0) * K + k0 + k8a], &As[(size_t)tid * 8]);
        gll16(&A[(size_t)(m0 + r1) * K + k0 + k8b], &As[(size_t)(tid + 256) * 8]);
        gll16(&B[(size_t)(n0 + r0) * K + k0 + k8a], &Bs[(size_t)tid * 8]);
        gll16(&B[(size_t)(n0 + r1) * K + k0 + k8b], &Bs[(size_t)(tid + 256) * 8]);
        __syncthreads();

        short8 af[4], bf[4];
#pragma unroll
        for (int mi = 0; mi < 4; ++mi)
            af[mi] = *(const short8*)&As[(size_t)(wm + mi * 16 + l15) * 32 + quad * 8];
#pragma unroll
        for (int ni = 0; ni < 4; ++ni)
            bf[ni] = *(const short8*)&Bs[(size_t)(wn + ni * 16 + l15) * 32 + quad * 8];
#pragma unroll
        for (int mi = 0; mi < 4; ++mi)
#pragma unroll
            for (int ni = 0; ni < 4; ++ni)
                acc[mi][ni] = __builtin_amdgcn_mfma_f32_16x16x32_bf16(
                    af[mi], bf[ni], acc[mi][ni], 0, 0, 0);
        __syncthreads();
    }

#pragma unroll
    for (int mi = 0; mi < 4; ++mi)
#pragma unroll
        for (int ni = 0; ni < 4; ++ni) {
            int col = n0 + wn + ni * 16 + l15;
#pragma unroll
            for (int r = 0; r < 4; ++r) {
                int row = m0 + wm + mi * 16 + quad * 4 + r;
                C[(size_t)row * N + col] = acc[mi][ni][r];
            }
        }
}

// --------------- depthwise causal conv (K=4) + bias + SiLU ------------------
__global__ __launch_bounds__(256)
void conv_silu_k(const float* __restrict__ proj, const float* __restrict__ cw,
                 const float* __restrict__ cb, float* __restrict__ convout)
{
    int idx = blockIdx.x * 256 + threadIdx.x;
    int d = idx % kConv, t = idx / kConv;
    float acc = cb[d];
#pragma unroll
    for (int k = 0; k < 4; ++k) {
        int ts = t + k - 3;
        float u = (ts >= 0) ? proj[(size_t)ts * kProjC + kI + d] : 0.f;
        acc += u * cw[d * 4 + k];
    }
    convout[idx] = siluf(acc);
}

// --------------- dt_raw fp32 dot + softplus + per-chunk cumsum --------------
__global__ __launch_bounds__(256)
void dt_cumsum_k(const float* __restrict__ x, const float* __restrict__ W_in,
                 const float* __restrict__ dt_bias, const float* __restrict__ A_log,
                 float* __restrict__ dt, float* __restrict__ acum)
{
    __shared__ float wrow[kHID];
    __shared__ float wsum[4];
    const int c = blockIdx.x >> 6, h = blockIdx.x & 63;
    const int l = threadIdx.x, t = c * kChunk + l;

    const float4* wr = (const float4*)&W_in[(size_t)(kI + kConv + h) * kHID];
#pragma unroll
    for (int i = 0; i < 2; ++i) ((float4*)wrow)[l + 256 * i] = wr[l + 256 * i];
    __syncthreads();

    const float4* xr = (const float4*)&x[(size_t)t * kHID];
    float4 s4 = make_float4(0.f, 0.f, 0.f, 0.f);
#pragma unroll 8
    for (int i = 0; i < kHID / 4; ++i) {
        float4 xv = xr[i];
        float4 wv = ((const float4*)wrow)[i];
        s4.x += xv.x * wv.x; s4.y += xv.y * wv.y;
        s4.z += xv.z * wv.z; s4.w += xv.w * wv.w;
    }
    float z = s4.x + s4.y + s4.z + s4.w + dt_bias[h];

    float a = -expf(A_log[h]);
    float d = (z > 20.f) ? z : log1pf(expf(z));
    dt[t * kH + h] = d;
    float v = d * a;
    int lane = l & 63, w = l >> 6;
#pragma unroll
    for (int off = 1; off < 64; off <<= 1) {
        float u = __shfl_up(v, off);
        if (lane >= off) v += u;
    }
    if (lane == 63) wsum[w] = v;
    __syncthreads();
    float add = 0.f;
    for (int i = 0; i < w; ++i) add += wsum[i];
    acum[t * kH + h] = v + add;
}

// --------------- per-chunk end states ---------------------------------------
__global__ __launch_bounds__(256)
void states_k(const float* __restrict__ conv, const float* __restrict__ dt,
              const float* __restrict__ acum, float* __restrict__ states)
{
    __shared__ float Bl[64][132];
    __shared__ float Xl[64][68];
    __shared__ float Wl[64];
    const int c = blockIdx.x >> 6, h = blockIdx.x & 63;
    const int tid = threadIdx.x;
    const int p = tid & 63, ng = tid >> 6;
    const float aend = acum[(size_t)(c * kChunk + 255) * kH + h];
    float4 acc[8];
#pragma unroll
    for (int i = 0; i < 8; ++i) acc[i] = make_float4(0.f, 0.f, 0.f, 0.f);

    for (int lt = 0; lt < 4; ++lt) {
        int tbase = c * kChunk + lt * 64;
#pragma unroll
        for (int r = 0; r < 8; ++r) {
            int f = tid + 256 * r;
            int ll = f >> 5, c4 = (f & 31) * 4;
            *(float4*)&Bl[ll][c4] =
                *(const float4*)&conv[(size_t)(tbase + ll) * kConv + kI + c4];
        }
#pragma unroll
        for (int r = 0; r < 4; ++r) {
            int f = tid + 256 * r;
            int ll = f >> 4, c4 = (f & 15) * 4;
            *(float4*)&Xl[ll][c4] =
                *(const float4*)&conv[(size_t)(tbase + ll) * kConv + h * kP + c4];
        }
        if (tid < 64) {
            int t = tbase + tid;
            Wl[tid] = __expf(aend - acum[(size_t)t * kH + h]) * dt[(size_t)t * kH + h];
        }
        __syncthreads();
        for (int ll = 0; ll < 64; ++ll) {
            float xv = Xl[ll][p] * Wl[ll];
#pragma unroll
            for (int j = 0; j < 8; ++j) {
                float4 b = *(const float4*)&Bl[ll][ng * 32 + j * 4];
                acc[j] = f4fma(xv, b, acc[j]);
            }
        }
        __syncthreads();
    }
    size_t base = ((size_t)(c * kH + h) * kP + p) * kN + ng * 32;
#pragma unroll
    for (int j = 0; j < 8; ++j) *(float4*)&states[base + j * 4] = acc[j];
}

// --------------- sequential inter-chunk recurrence (8 chunks) ---------------
__global__ __launch_bounds__(256)
void scan_k(const float* __restrict__ states, const float* __restrict__ acum,
            float* __restrict__ prev)
{
    const int h = blockIdx.x >> 3, seg = blockIdx.x & 7;
    const int e = (seg * 256 + threadIdx.x) * 4;
    float4 carry = make_float4(0.f, 0.f, 0.f, 0.f);
    for (int c = 0; c < kNC; ++c) {
        size_t base = (size_t)(c * kH + h) * (kP * kN);
        *(float4*)&prev[base + e] = carry;
        float dec = __expf(acum[(size_t)(c * kChunk + 255) * kH + h]);
        float4 st = *(const float4*)&states[base + e];
        carry.x = carry.x * dec + st.x; carry.y = carry.y * dec + st.y;
        carry.z = carry.z * dec + st.z; carry.w = carry.w * dec + st.w;
    }
}

// --------------- SSD Y (v3): bf16 MFMA flash-style --------------------------
// block = (c, h, ti): 64 t-rows x 64 p. 4 waves, wave w owns rows w*16..w*16+15.
// Products: inter Y=C.prev^T (K=128), S=C.B^T (K=128), Y+=W.X^T (K=64), all
// mfma_f32_16x16x32_bf16. Weighting fp32 in C/D layout (col=lane&15,
// row=quad*4+r); D-skip folded into W diagonal. LDS rows 16B-aligned,
// stride 136/72 bf16 -> <=2-way conflicts on frag reads. LDS 54KB, 2 blk/CU.
__global__ __launch_bounds__(256)
void ssd_y3_k(const float* __restrict__ conv, const float* __restrict__ dt,
              const float* __restrict__ acum, const float* __restrict__ prev,
              const float* __restrict__ Dp, float* __restrict__ Y)
{
    __shared__ unsigned short Cb[64 * 136];  // C[t][n]
    __shared__ unsigned short Bb[64 * 136];  // prev[p][n], then B[s][n] per si
    __shared__ unsigned short Xt[64 * 72];   // X^T [p][s] per si
    __shared__ unsigned short Wb[64 * 72];   // W [t][s] (wave-private strips)
    __shared__ float At[64], Asv[64], Dtv[64];

    const int bi = blockIdx.x;
    const int ti = bi & 3, h = (bi >> 2) & 63, c = bi >> 8;
    const int tid = threadIdx.x;
    const int wave = tid >> 6, lane = tid & 63;
    const int quad = lane >> 4, l15 = lane & 15;
    const int trow0 = c * kChunk + ti * 64;
    const float Dh = Dp[h];

    // stage C tile [64][128] and prev [64p][128n] (into Bb), fp32->bf16
#pragma unroll
    for (int r = 0; r < 8; ++r) {
        int f = tid + 256 * r;
        int row = f >> 5, c4 = (f & 31) * 4;
        float4 v = *(const float4*)&conv[(size_t)(trow0 + row) * kConv + kI + kN + c4];
        ushort4 u = {f2bf(v.x), f2bf(v.y), f2bf(v.z), f2bf(v.w)};
        *(ushort4*)&Cb[row * 136 + c4] = u;
    }
    const size_t pbase = (size_t)(c * kH + h) * (kP * kN);
#pragma unroll
    for (int r = 0; r < 8; ++r) {
        int f = tid + 256 * r;
        int row = f >> 5, c4 = (f & 31) * 4;
        float4 v = *(const float4*)&prev[pbase + (size_t)row * kN + c4];
        ushort4 u = {f2bf(v.x), f2bf(v.y), f2bf(v.z), f2bf(v.w)};
        *(ushort4*)&Bb[row * 136 + c4] = u;
    }
    if (tid < 64) At[tid] = acum[(size_t)(trow0 + tid) * kH + h];
    __syncthreads();

    // inter-chunk: yacc = C . prev^T
    floatx4 yacc[4] = {};
#pragma unroll
    for (int ks = 0; ks < 4; ++ks) {
        short8 a = *(const short8*)&Cb[(wave * 16 + l15) * 136 + ks * 32 + quad * 8];
#pragma unroll
        for (int ni = 0; ni < 4; ++ni) {
            short8 b = *(const short8*)&Bb[(ni * 16 + l15) * 136 + ks * 32 + quad * 8];
            yacc[ni] = __builtin_amdgcn_mfma_f32_16x16x32_bf16(a, b, yacc[ni], 0, 0, 0);
        }
    }
    {   // scale by exp(Acum_t)
        float eAr[4];
#pragma unroll
        for (int r = 0; r < 4; ++r) eAr[r] = __expf(At[wave * 16 + quad * 4 + r]);
#pragma unroll
        for (int ni = 0; ni < 4; ++ni)
#pragma unroll
            for (int r = 0; r < 4; ++r) yacc[ni][r] *= eAr[r];
    }

    // causal si loop
    for (int si = 0; si <= ti; ++si) {
        const int srow0 = c * kChunk + si * 64;
        __syncthreads();   // prior reads of Bb/Xt done before overwrite
#pragma unroll
        for (int r = 0; r < 8; ++r) {   // B rows [64][128]
            int f = tid + 256 * r;
            int row = f >> 5, c4 = (f & 31) * 4;
            float4 v = *(const float4*)&conv[(size_t)(srow0 + row) * kConv + kI + c4];
            ushort4 u = {f2bf(v.x), f2bf(v.y), f2bf(v.z), f2bf(v.w)};
            *(ushort4*)&Bb[row * 136 + c4] = u;
        }
#pragma unroll
        for (int it = 0; it < 2; ++it) {  // X^T: lane reads a column segment
            int f = tid + 256 * it;
            int p = f & 63, sb = (f >> 6) * 8;
            float vs[8];
#pragma unroll
            for (int j = 0; j < 8; ++j)
                vs[j] = conv[(size_t)(srow0 + sb + j) * kConv + h * kP + p];
            ushort4 u0 = {f2bf(vs[0]), f2bf(vs[1]), f2bf(vs[2]), f2bf(vs[3])};
            ushort4 u1 = {f2bf(vs[4]), f2bf(vs[5]), f2bf(vs[6]), f2bf(vs[7])};
            *(ushort4*)&Xt[p * 72 + sb] = u0;
            *(ushort4*)&Xt[p * 72 + sb + 4] = u1;
        }
        if (tid < 64) {
            Asv[tid] = acum[(size_t)(srow0 + tid) * kH + h];
            Dtv[tid] = dt[(size_t)(srow0 + tid) * kH + h];
        }
        __syncthreads();

        // S = C . B^T
        floatx4 sacc[4] = {};
#pragma unroll
        for (int ks = 0; ks < 4; ++ks) {
            short8 a = *(const short8*)&Cb[(wave * 16 + l15) * 136 + ks * 32 + quad * 8];
#pragma unroll
            for (int ni = 0; ni < 4; ++ni) {
                short8 b = *(const short8*)&Bb[(ni * 16 + l15) * 136 + ks * 32 + quad * 8];
                sacc[ni] = __builtin_amdgcn_mfma_f32_16x16x32_bf16(a, b, sacc[ni], 0, 0, 0);
            }
        }

        // weight (fp32) -> Wb[t][s] bf16; D folded into diagonal
        const bool diag = (si == ti);
#pragma unroll
        for (int ni = 0; ni < 4; ++ni) {
            int s_ = ni * 16 + l15;
            float as = Asv[s_], dts = Dtv[s_];
#pragma unroll
            for (int r = 0; r < 4; ++r) {
                int tl = wave * 16 + quad * 4 + r;
                float w = sacc[ni][r] * __expf(At[tl] - as) * dts;
                if (diag) {
                    if (s_ > tl) w = 0.f;
                    else if (s_ == tl) w += Dh;
                }
                Wb[tl * 72 + s_] = f2bf(w);
            }
        }
        // same-wave LDS write->read (wave-private strip): no barrier needed
#pragma unroll
        for (int ks = 0; ks < 2; ++ks) {
            short8 aw = *(const short8*)&Wb[(wave * 16 + l15) * 72 + ks * 32 + quad * 8];
#pragma unroll
            for (int ni = 0; ni < 4; ++ni) {
                short8 xb = *(const short8*)&Xt[(ni * 16 + l15) * 72 + ks * 32 + quad * 8];
                yacc[ni] = __builtin_amdgcn_mfma_f32_16x16x32_bf16(aw, xb, yacc[ni], 0, 0, 0);
            }
        }
    }

#pragma unroll
    for (int ni = 0; ni < 4; ++ni)
#pragma unroll
        for (int r = 0; r < 4; ++r)
            Y[(size_t)(trow0 + wave * 16 + quad * 4 + r) * kI + h * kP + ni * 16 + l15]
                = yacc[ni][r];
}

// --------------- gated RMSNorm -> bf16 output for final MFMA GEMM -----------
__global__ __launch_bounds__(256)
void rmsnorm_gate_k(const float* __restrict__ Y, const float* __restrict__ proj,
                    const float* __restrict__ nw, unsigned short* __restrict__ Yb)
{
    __shared__ float red[4];
    const int t = blockIdx.x, tid = threadIdx.x;
    const float* yrow = &Y[(size_t)t * kI];
    const float* grow = &proj[(size_t)t * kProjC];
    float v[16];
    float ss = 0.f;
#pragma unroll
    for (int j = 0; j < 4; ++j) {
        int i = (tid + 256 * j) * 4;
        float4 y4 = *(const float4*)&yrow[i];
        float4 g4 = *(const float4*)&grow[i];
        float a = y4.x * siluf(g4.x), bq = y4.y * siluf(g4.y);
        float cq = y4.z * siluf(g4.z), d = y4.w * siluf(g4.w);
        v[j * 4 + 0] = a; v[j * 4 + 1] = bq; v[j * 4 + 2] = cq; v[j * 4 + 3] = d;
        ss += a * a + bq * bq + cq * cq + d * d;
    }
#pragma unroll
    for (int off = 32; off > 0; off >>= 1) ss += __shfl_down(ss, off);
    if ((tid & 63) == 0) red[tid >> 6] = ss;
    __syncthreads();
    float sum = red[0] + red[1] + red[2] + red[3];
    float rr = rsqrtf(sum * (1.f / kI) + kEps);
#pragma unroll
    for (int j = 0; j < 4; ++j) {
        int i = (tid + 256 * j) * 4;
        float4 w4 = *(const float4*)&nw[i];
        ushort4 o;
        o.x = f2bf(v[j * 4 + 0] * rr * w4.x);
        o.y = f2bf(v[j * 4 + 1] * rr * w4.y);
        o.z = f2bf(v[j * 4 + 2] * rr * w4.z);
        o.w = f2bf(v[j * 4 + 3] * rr * w4.w);
        *(ushort4*)&Yb[(size_t)t * kI + i] = o;
    }
}

extern "C" void kernel_launch(void* const* d_in, const int* in_sizes, int n_in,
                              void* d_out, int out_size, void* d_ws, size_t ws_size,
                              hipStream_t stream)
{
    const float* x       = (const float*)d_in[0];
    const float* W_in    = (const float*)d_in[1];
    const float* conv_w  = (const float*)d_in[2];
    const float* conv_b  = (const float*)d_in[3];
    const float* dt_bias = (const float*)d_in[4];
    const float* A_log   = (const float*)d_in[5];
    const float* Dp      = (const float*)d_in[6];
    const float* norm_w  = (const float*)d_in[7];
    const float* W_out   = (const float*)d_in[8];
    float* out = (float*)d_out;

    float* ws   = (float*)d_ws;
    float* proj = ws;                                    // 2048*8448
    float* conv = proj + (size_t)kS * kProjC;            // 2048*4352
    float* dtb  = conv + (size_t)kS * kConv;             // 2048*64
    float* acum = dtb + (size_t)kS * kH;                 // 2048*64
    float* R1   = acum + (size_t)kS * kH;                // 12,582,912 floats
    float* prev   = R1;                                  // 4,194,304
    float* Y      = R1 + (size_t)kNC * kH * kP * kN;     // 8,388,608
    float* states = Y;
    unsigned short* Wb  = (unsigned short*)R1;           // 8448*2048 bf16 (early)
    unsigned short* Yb  = (unsigned short*)R1;           // 2048*4096 bf16 (late)
    unsigned short* xb  = (unsigned short*)conv;         // 2048*2048 bf16 (early)
    unsigned short* Wob = (unsigned short*)conv;         // 2048*4096 bf16 (late)

    dim3 blk(256);
    cast_bf16_k<<<(kS * kHID) / 2048, blk, 0, stream>>>(x, xb);
    cast_bf16_k<<<(kProjC * kHID) / 2048, blk, 0, stream>>>(W_in, Wb);
    gemm_bt_bf16<<<dim3(kProjC / 128, kS / 128), blk, 0, stream>>>(
        xb, Wb, proj, kS, kProjC, kHID);
    conv_silu_k<<<(kS * kConv) / 256, blk, 0, stream>>>(proj, conv_w, conv_b, conv);
    dt_cumsum_k<<<kNC * kH, blk, 0, stream>>>(x, W_in, dt_bias, A_log, dtb, acum);
    states_k<<<kNC * kH, blk, 0, stream>>>(conv, dtb, acum, states);
    scan_k<<<kH * 8, blk, 0, stream>>>(states, acum, prev);
    ssd_y3_k<<<kNC * kH * 4, blk, 0, stream>>>(conv, dtb, acum, prev, Dp, Y);
    rmsnorm_gate_k<<<kS, blk, 0, stream>>>(Y, proj, norm_w, Yb);
    cast_bf16_k<<<(kHID * kI) / 2048, blk, 0, stream>>>(W_out, Wob);
    gemm_bt_bf16<<<dim3(kHID / 128, kS / 128), blk, 0, stream>>>(
        Yb, Wob, out, kS, kHID, kI);
}

// Round 5
// 641.757 us; speedup vs baseline: 5.3878x; 1.0060x over previous
//
#include <hip/hip_runtime.h>
#include <math.h>

// Bamba-9B mixer, b=1 s=2048. Round 4: GEMM fixes —
//  (a) XOR-swizzled LDS chunk index kills the 8-way bank conflict on frag reads
//  (b) M-fastest block order: consecutive blocks share a B-tile, stream A (L2-resident)
static constexpr int kS     = 2048;
static constexpr int kHID   = 2048;
static constexpr int kI     = 4096;
static constexpr int kH     = 64;
static constexpr int kP     = 64;
static constexpr int kN     = 128;
static constexpr int kConv  = 4352;   // I + 2*G*N
static constexpr int kProjC = 8448;   // I + CONV  (gate + conv cols only; dt separate)
static constexpr int kChunk = 256;
static constexpr int kNC    = 8;
static constexpr float kEps = 1e-5f;

typedef __attribute__((ext_vector_type(8))) short short8;    // 8 x bf16 fragment
typedef __attribute__((ext_vector_type(4))) float floatx4;   // MFMA accumulator

__device__ __forceinline__ float4 f4fma(float a, float4 b, float4 c) {
    c.x += a * b.x; c.y += a * b.y; c.z += a * b.z; c.w += a * b.w; return c;
}
__device__ __forceinline__ float siluf(float x) {
    return x / (1.f + __expf(-x));
}
__device__ __forceinline__ unsigned short f2bf(float f) {   // RNE, finite inputs
    unsigned int u = __float_as_uint(f);
    return (unsigned short)((u + 0x7FFFu + ((u >> 16) & 1u)) >> 16);
}
__device__ __forceinline__ void gll16(const void* g, void* l) {
    __builtin_amdgcn_global_load_lds(
        (const __attribute__((address_space(1))) void*)g,
        (__attribute__((address_space(3))) void*)l, 16, 0, 0);
}

// ---------- fp32 -> bf16 cast, 8 elems/thread ----------
__global__ __launch_bounds__(256)
void cast_bf16_k(const float* __restrict__ in, unsigned short* __restrict__ out)
{
    size_t i = ((size_t)blockIdx.x * 256 + threadIdx.x) * 8;
    float4 a = *(const float4*)&in[i];
    float4 b = *(const float4*)&in[i + 4];
    ushort4 u0 = {f2bf(a.x), f2bf(a.y), f2bf(a.z), f2bf(a.w)};
    ushort4 u1 = {f2bf(b.x), f2bf(b.y), f2bf(b.z), f2bf(b.w)};
    *(ushort4*)&out[i] = u0;
    *(ushort4*)&out[i + 4] = u1;
}

// ---------- bf16 MFMA NT GEMM: C[M,N] = A[M,K] * B[N,K]^T ----------
// 256 thr = 4 waves, tile 128x128, BK=32, mfma_f32_16x16x32_bf16.
// LDS [row][chunk]: physical 16B-chunk slot = logical_chunk ^ ((row>>1)&3)
// -> frag reads land 2-way per bank (free) instead of 8-way.
// Grid: blockIdx.x = M-tile (fastest) so consecutive blocks share a B-tile.
__global__ __launch_bounds__(256)
void gemm_bt_bf16(const unsigned short* __restrict__ A,
                  const unsigned short* __restrict__ B,
                  float* __restrict__ C, int M, int N, int K)
{
    __shared__ unsigned short As[128 * 32];
    __shared__ unsigned short Bs[128 * 32];
    const int tid = threadIdx.x;
    const int lane = tid & 63, quad = lane >> 4, l15 = lane & 15;
    const int wave = tid >> 6;
    const int m0 = blockIdx.x * 128, n0 = blockIdx.y * 128;
    const int wm = (wave & 1) * 64, wn = (wave >> 1) * 64;

    floatx4 acc[4][4] = {};

    // staging: lane f writes LDS bytes [f*16,f*16+16) = row f>>2, phys chunk f&3.
    // source logical chunk = (f&3) ^ s(row), s(row)=(row>>1)&3 (same 64B line).
    const int r0 = tid >> 2,         c0 = ((tid & 3) ^ ((r0 >> 1) & 3)) * 8;
    const int r1 = (tid + 256) >> 2, c1 = ((tid & 3) ^ ((r1 >> 1) & 3)) * 8;

    // fragment read offsets (logical chunk = quad, row = w*+mi*16+l15)
    const int sA = ((quad ^ (((wm + l15) >> 1) & 3)) * 8);   // row>>1 parity uses l15 only
    const int sB = ((quad ^ (((wn + l15) >> 1) & 3)) * 8);

    for (int k0 = 0; k0 < K; k0 += 32) {
        gll16(&A[(size_t)(m0 + r0) * K + k0 + c0], &As[(size_t)tid * 8]);
        gll16(&A[(size_t)(m0 + r1) * K + k0 + c1], &As[(size_t)(tid + 256) * 8]);
        gll16(&B[(size_t)(n0 + r0) * K + k0 + c0], &Bs[(size_t)tid * 8]);
        gll16(&B[(size_t)(n0 + r1) * K + k0 + c1], &Bs[(size_t)(tid + 256) * 8]);
        __syncthreads();

        short8 af[4], bf[4];
#pragma unroll
        for (int mi = 0; mi < 4; ++mi)
            af[mi] = *(const short8*)&As[(size_t)(wm + mi * 16 + l15) * 32 + sA];
#pragma unroll
        for (int ni = 0; ni < 4; ++ni)
            bf[ni] = *(const short8*)&Bs[(size_t)(wn + ni * 16 + l15) * 32 + sB];
#pragma unroll
        for (int mi = 0; mi < 4; ++mi)
#pragma unroll
            for (int ni = 0; ni < 4; ++ni)
                acc[mi][ni] = __builtin_amdgcn_mfma_f32_16x16x32_bf16(
                    af[mi], bf[ni], acc[mi][ni], 0, 0, 0);
        __syncthreads();
    }

#pragma unroll
    for (int mi = 0; mi < 4; ++mi)
#pragma unroll
        for (int ni = 0; ni < 4; ++ni) {
            int col = n0 + wn + ni * 16 + l15;
#pragma unroll
            for (int r = 0; r < 4; ++r) {
                int row = m0 + wm + mi * 16 + quad * 4 + r;
                C[(size_t)row * N + col] = acc[mi][ni][r];
            }
        }
}

// --------------- depthwise causal conv (K=4) + bias + SiLU ------------------
__global__ __launch_bounds__(256)
void conv_silu_k(const float* __restrict__ proj, const float* __restrict__ cw,
                 const float* __restrict__ cb, float* __restrict__ convout)
{
    int idx = blockIdx.x * 256 + threadIdx.x;
    int d = idx % kConv, t = idx / kConv;
    float acc = cb[d];
#pragma unroll
    for (int k = 0; k < 4; ++k) {
        int ts = t + k - 3;
        float u = (ts >= 0) ? proj[(size_t)ts * kProjC + kI + d] : 0.f;
        acc += u * cw[d * 4 + k];
    }
    convout[idx] = siluf(acc);
}

// --------------- dt_raw fp32 dot + softplus + per-chunk cumsum --------------
__global__ __launch_bounds__(256)
void dt_cumsum_k(const float* __restrict__ x, const float* __restrict__ W_in,
                 const float* __restrict__ dt_bias, const float* __restrict__ A_log,
                 float* __restrict__ dt, float* __restrict__ acum)
{
    __shared__ float wrow[kHID];
    __shared__ float wsum[4];
    const int c = blockIdx.x >> 6, h = blockIdx.x & 63;
    const int l = threadIdx.x, t = c * kChunk + l;

    const float4* wr = (const float4*)&W_in[(size_t)(kI + kConv + h) * kHID];
#pragma unroll
    for (int i = 0; i < 2; ++i) ((float4*)wrow)[l + 256 * i] = wr[l + 256 * i];
    __syncthreads();

    const float4* xr = (const float4*)&x[(size_t)t * kHID];
    float4 s4 = make_float4(0.f, 0.f, 0.f, 0.f);
#pragma unroll 8
    for (int i = 0; i < kHID / 4; ++i) {
        float4 xv = xr[i];
        float4 wv = ((const float4*)wrow)[i];
        s4.x += xv.x * wv.x; s4.y += xv.y * wv.y;
        s4.z += xv.z * wv.z; s4.w += xv.w * wv.w;
    }
    float z = s4.x + s4.y + s4.z + s4.w + dt_bias[h];

    float a = -expf(A_log[h]);
    float d = (z > 20.f) ? z : log1pf(expf(z));
    dt[t * kH + h] = d;
    float v = d * a;
    int lane = l & 63, w = l >> 6;
#pragma unroll
    for (int off = 1; off < 64; off <<= 1) {
        float u = __shfl_up(v, off);
        if (lane >= off) v += u;
    }
    if (lane == 63) wsum[w] = v;
    __syncthreads();
    float add = 0.f;
    for (int i = 0; i < w; ++i) add += wsum[i];
    acum[t * kH + h] = v + add;
}

// --------------- per-chunk end states ---------------------------------------
__global__ __launch_bounds__(256)
void states_k(const float* __restrict__ conv, const float* __restrict__ dt,
              const float* __restrict__ acum, float* __restrict__ states)
{
    __shared__ float Bl[64][132];
    __shared__ float Xl[64][68];
    __shared__ float Wl[64];
    const int c = blockIdx.x >> 6, h = blockIdx.x & 63;
    const int tid = threadIdx.x;
    const int p = tid & 63, ng = tid >> 6;
    const float aend = acum[(size_t)(c * kChunk + 255) * kH + h];
    float4 acc[8];
#pragma unroll
    for (int i = 0; i < 8; ++i) acc[i] = make_float4(0.f, 0.f, 0.f, 0.f);

    for (int lt = 0; lt < 4; ++lt) {
        int tbase = c * kChunk + lt * 64;
#pragma unroll
        for (int r = 0; r < 8; ++r) {
            int f = tid + 256 * r;
            int ll = f >> 5, c4 = (f & 31) * 4;
            *(float4*)&Bl[ll][c4] =
                *(const float4*)&conv[(size_t)(tbase + ll) * kConv + kI + c4];
        }
#pragma unroll
        for (int r = 0; r < 4; ++r) {
            int f = tid + 256 * r;
            int ll = f >> 4, c4 = (f & 15) * 4;
            *(float4*)&Xl[ll][c4] =
                *(const float4*)&conv[(size_t)(tbase + ll) * kConv + h * kP + c4];
        }
        if (tid < 64) {
            int t = tbase + tid;
            Wl[tid] = __expf(aend - acum[(size_t)t * kH + h]) * dt[(size_t)t * kH + h];
        }
        __syncthreads();
        for (int ll = 0; ll < 64; ++ll) {
            float xv = Xl[ll][p] * Wl[ll];
#pragma unroll
            for (int j = 0; j < 8; ++j) {
                float4 b = *(const float4*)&Bl[ll][ng * 32 + j * 4];
                acc[j] = f4fma(xv, b, acc[j]);
            }
        }
        __syncthreads();
    }
    size_t base = ((size_t)(c * kH + h) * kP + p) * kN + ng * 32;
#pragma unroll
    for (int j = 0; j < 8; ++j) *(float4*)&states[base + j * 4] = acc[j];
}

// --------------- sequential inter-chunk recurrence (8 chunks) ---------------
__global__ __launch_bounds__(256)
void scan_k(const float* __restrict__ states, const float* __restrict__ acum,
            float* __restrict__ prev)
{
    const int h = blockIdx.x >> 3, seg = blockIdx.x & 7;
    const int e = (seg * 256 + threadIdx.x) * 4;
    float4 carry = make_float4(0.f, 0.f, 0.f, 0.f);
    for (int c = 0; c < kNC; ++c) {
        size_t base = (size_t)(c * kH + h) * (kP * kN);
        *(float4*)&prev[base + e] = carry;
        float dec = __expf(acum[(size_t)(c * kChunk + 255) * kH + h]);
        float4 st = *(const float4*)&states[base + e];
        carry.x = carry.x * dec + st.x; carry.y = carry.y * dec + st.y;
        carry.z = carry.z * dec + st.z; carry.w = carry.w * dec + st.w;
    }
}

// --------------- SSD Y (v3): bf16 MFMA flash-style --------------------------
__global__ __launch_bounds__(256)
void ssd_y3_k(const float* __restrict__ conv, const float* __restrict__ dt,
              const float* __restrict__ acum, const float* __restrict__ prev,
              const float* __restrict__ Dp, float* __restrict__ Y)
{
    __shared__ unsigned short Cb[64 * 136];  // C[t][n]
    __shared__ unsigned short Bb[64 * 136];  // prev[p][n], then B[s][n] per si
    __shared__ unsigned short Xt[64 * 72];   // X^T [p][s] per si
    __shared__ unsigned short Wb[64 * 72];   // W [t][s] (wave-private strips)
    __shared__ float At[64], Asv[64], Dtv[64];

    const int bi = blockIdx.x;
    const int ti = bi & 3, h = (bi >> 2) & 63, c = bi >> 8;
    const int tid = threadIdx.x;
    const int wave = tid >> 6, lane = tid & 63;
    const int quad = lane >> 4, l15 = lane & 15;
    const int trow0 = c * kChunk + ti * 64;
    const float Dh = Dp[h];

#pragma unroll
    for (int r = 0; r < 8; ++r) {
        int f = tid + 256 * r;
        int row = f >> 5, c4 = (f & 31) * 4;
        float4 v = *(const float4*)&conv[(size_t)(trow0 + row) * kConv + kI + kN + c4];
        ushort4 u = {f2bf(v.x), f2bf(v.y), f2bf(v.z), f2bf(v.w)};
        *(ushort4*)&Cb[row * 136 + c4] = u;
    }
    const size_t pbase = (size_t)(c * kH + h) * (kP * kN);
#pragma unroll
    for (int r = 0; r < 8; ++r) {
        int f = tid + 256 * r;
        int row = f >> 5, c4 = (f & 31) * 4;
        float4 v = *(const float4*)&prev[pbase + (size_t)row * kN + c4];
        ushort4 u = {f2bf(v.x), f2bf(v.y), f2bf(v.z), f2bf(v.w)};
        *(ushort4*)&Bb[row * 136 + c4] = u;
    }
    if (tid < 64) At[tid] = acum[(size_t)(trow0 + tid) * kH + h];
    __syncthreads();

    floatx4 yacc[4] = {};
#pragma unroll
    for (int ks = 0; ks < 4; ++ks) {
        short8 a = *(const short8*)&Cb[(wave * 16 + l15) * 136 + ks * 32 + quad * 8];
#pragma unroll
        for (int ni = 0; ni < 4; ++ni) {
            short8 b = *(const short8*)&Bb[(ni * 16 + l15) * 136 + ks * 32 + quad * 8];
            yacc[ni] = __builtin_amdgcn_mfma_f32_16x16x32_bf16(a, b, yacc[ni], 0, 0, 0);
        }
    }
    {
        float eAr[4];
#pragma unroll
        for (int r = 0; r < 4; ++r) eAr[r] = __expf(At[wave * 16 + quad * 4 + r]);
#pragma unroll
        for (int ni = 0; ni < 4; ++ni)
#pragma unroll
            for (int r = 0; r < 4; ++r) yacc[ni][r] *= eAr[r];
    }

    for (int si = 0; si <= ti; ++si) {
        const int srow0 = c * kChunk + si * 64;
        __syncthreads();
#pragma unroll
        for (int r = 0; r < 8; ++r) {
            int f = tid + 256 * r;
            int row = f >> 5, c4 = (f & 31) * 4;
            float4 v = *(const float4*)&conv[(size_t)(srow0 + row) * kConv + kI + c4];
            ushort4 u = {f2bf(v.x), f2bf(v.y), f2bf(v.z), f2bf(v.w)};
            *(ushort4*)&Bb[row * 136 + c4] = u;
        }
#pragma unroll
        for (int it = 0; it < 2; ++it) {
            int f = tid + 256 * it;
            int p = f & 63, sb = (f >> 6) * 8;
            float vs[8];
#pragma unroll
            for (int j = 0; j < 8; ++j)
                vs[j] = conv[(size_t)(srow0 + sb + j) * kConv + h * kP + p];
            ushort4 u0 = {f2bf(vs[0]), f2bf(vs[1]), f2bf(vs[2]), f2bf(vs[3])};
            ushort4 u1 = {f2bf(vs[4]), f2bf(vs[5]), f2bf(vs[6]), f2bf(vs[7])};
            *(ushort4*)&Xt[p * 72 + sb] = u0;
            *(ushort4*)&Xt[p * 72 + sb + 4] = u1;
        }
        if (tid < 64) {
            Asv[tid] = acum[(size_t)(srow0 + tid) * kH + h];
            Dtv[tid] = dt[(size_t)(srow0 + tid) * kH + h];
        }
        __syncthreads();

        floatx4 sacc[4] = {};
#pragma unroll
        for (int ks = 0; ks < 4; ++ks) {
            short8 a = *(const short8*)&Cb[(wave * 16 + l15) * 136 + ks * 32 + quad * 8];
#pragma unroll
            for (int ni = 0; ni < 4; ++ni) {
                short8 b = *(const short8*)&Bb[(ni * 16 + l15) * 136 + ks * 32 + quad * 8];
                sacc[ni] = __builtin_amdgcn_mfma_f32_16x16x32_bf16(a, b, sacc[ni], 0, 0, 0);
            }
        }

        const bool diag = (si == ti);
#pragma unroll
        for (int ni = 0; ni < 4; ++ni) {
            int s_ = ni * 16 + l15;
            float as = Asv[s_], dts = Dtv[s_];
#pragma unroll
            for (int r = 0; r < 4; ++r) {
                int tl = wave * 16 + quad * 4 + r;
                float w = sacc[ni][r] * __expf(At[tl] - as) * dts;
                if (diag) {
                    if (s_ > tl) w = 0.f;
                    else if (s_ == tl) w += Dh;
                }
                Wb[tl * 72 + s_] = f2bf(w);
            }
        }
#pragma unroll
        for (int ks = 0; ks < 2; ++ks) {
            short8 aw = *(const short8*)&Wb[(wave * 16 + l15) * 72 + ks * 32 + quad * 8];
#pragma unroll
            for (int ni = 0; ni < 4; ++ni) {
                short8 xb = *(const short8*)&Xt[(ni * 16 + l15) * 72 + ks * 32 + quad * 8];
                yacc[ni] = __builtin_amdgcn_mfma_f32_16x16x32_bf16(aw, xb, yacc[ni], 0, 0, 0);
            }
        }
    }

#pragma unroll
    for (int ni = 0; ni < 4; ++ni)
#pragma unroll
        for (int r = 0; r < 4; ++r)
            Y[(size_t)(trow0 + wave * 16 + quad * 4 + r) * kI + h * kP + ni * 16 + l15]
                = yacc[ni][r];
}

// --------------- gated RMSNorm -> bf16 output for final MFMA GEMM -----------
__global__ __launch_bounds__(256)
void rmsnorm_gate_k(const float* __restrict__ Y, const float* __restrict__ proj,
                    const float* __restrict__ nw, unsigned short* __restrict__ Yb)
{
    __shared__ float red[4];
    const int t = blockIdx.x, tid = threadIdx.x;
    const float* yrow = &Y[(size_t)t * kI];
    const float* grow = &proj[(size_t)t * kProjC];
    float v[16];
    float ss = 0.f;
#pragma unroll
    for (int j = 0; j < 4; ++j) {
        int i = (tid + 256 * j) * 4;
        float4 y4 = *(const float4*)&yrow[i];
        float4 g4 = *(const float4*)&grow[i];
        float a = y4.x * siluf(g4.x), bq = y4.y * siluf(g4.y);
        float cq = y4.z * siluf(g4.z), d = y4.w * siluf(g4.w);
        v[j * 4 + 0] = a; v[j * 4 + 1] = bq; v[j * 4 + 2] = cq; v[j * 4 + 3] = d;
        ss += a * a + bq * bq + cq * cq + d * d;
    }
#pragma unroll
    for (int off = 32; off > 0; off >>= 1) ss += __shfl_down(ss, off);
    if ((tid & 63) == 0) red[tid >> 6] = ss;
    __syncthreads();
    float sum = red[0] + red[1] + red[2] + red[3];
    float rr = rsqrtf(sum * (1.f / kI) + kEps);
#pragma unroll
    for (int j = 0; j < 4; ++j) {
        int i = (tid + 256 * j) * 4;
        float4 w4 = *(const float4*)&nw[i];
        ushort4 o;
        o.x = f2bf(v[j * 4 + 0] * rr * w4.x);
        o.y = f2bf(v[j * 4 + 1] * rr * w4.y);
        o.z = f2bf(v[j * 4 + 2] * rr * w4.z);
        o.w = f2bf(v[j * 4 + 3] * rr * w4.w);
        *(ushort4*)&Yb[(size_t)t * kI + i] = o;
    }
}

extern "C" void kernel_launch(void* const* d_in, const int* in_sizes, int n_in,
                              void* d_out, int out_size, void* d_ws, size_t ws_size,
                              hipStream_t stream)
{
    const float* x       = (const float*)d_in[0];
    const float* W_in    = (const float*)d_in[1];
    const float* conv_w  = (const float*)d_in[2];
    const float* conv_b  = (const float*)d_in[3];
    const float* dt_bias = (const float*)d_in[4];
    const float* A_log   = (const float*)d_in[5];
    const float* Dp      = (const float*)d_in[6];
    const float* norm_w  = (const float*)d_in[7];
    const float* W_out   = (const float*)d_in[8];
    float* out = (float*)d_out;

    float* ws   = (float*)d_ws;
    float* proj = ws;                                    // 2048*8448
    float* conv = proj + (size_t)kS * kProjC;            // 2048*4352
    float* dtb  = conv + (size_t)kS * kConv;             // 2048*64
    float* acum = dtb + (size_t)kS * kH;                 // 2048*64
    float* R1   = acum + (size_t)kS * kH;                // 12,582,912 floats
    float* prev   = R1;                                  // 4,194,304
    float* Y      = R1 + (size_t)kNC * kH * kP * kN;     // 8,388,608
    float* states = Y;
    unsigned short* Wb  = (unsigned short*)R1;           // 8448*2048 bf16 (early)
    unsigned short* Yb  = (unsigned short*)R1;           // 2048*4096 bf16 (late)
    unsigned short* xb  = (unsigned short*)conv;         // 2048*2048 bf16 (early)
    unsigned short* Wob = (unsigned short*)conv;         // 2048*4096 bf16 (late)

    dim3 blk(256);
    cast_bf16_k<<<(kS * kHID) / 2048, blk, 0, stream>>>(x, xb);
    cast_bf16_k<<<(kProjC * kHID) / 2048, blk, 0, stream>>>(W_in, Wb);
    gemm_bt_bf16<<<dim3(kS / 128, kProjC / 128), blk, 0, stream>>>(
        xb, Wb, proj, kS, kProjC, kHID);
    conv_silu_k<<<(kS * kConv) / 256, blk, 0, stream>>>(proj, conv_w, conv_b, conv);
    dt_cumsum_k<<<kNC * kH, blk, 0, stream>>>(x, W_in, dt_bias, A_log, dtb, acum);
    states_k<<<kNC * kH, blk, 0, stream>>>(conv, dtb, acum, states);
    scan_k<<<kH * 8, blk, 0, stream>>>(states, acum, prev);
    ssd_y3_k<<<kNC * kH * 4, blk, 0, stream>>>(conv, dtb, acum, prev, Dp, Y);
    rmsnorm_gate_k<<<kS, blk, 0, stream>>>(Y, proj, norm_w, Yb);
    cast_bf16_k<<<(kHID * kI) / 2048, blk, 0, stream>>>(W_out, Wob);
    gemm_bt_bf16<<<dim3(kS / 128, kHID / 128), blk, 0, stream>>>(
        Yb, Wob, out, kS, kHID, kI);
}

// Round 6
// 523.460 us; speedup vs baseline: 6.6054x; 1.2260x over previous
//
#include <hip/hip_runtime.h>
#include <math.h>

// Bamba-9B mixer, b=1 s=2048. Round 5:
//  (a) GEMM: XCD-affinity swizzle (16 M-blocks of an N-col -> one XCD's L2)
//  (b) GEMM: BK=64 -> half the barrier/vmcnt(0) drains per K-loop
//  (c) dt_raw folded into bf16 proj GEMM (kProj=8512, tail tile guarded);
//      dt_cumsum reduced to a trivial scan (kills ~1GB of x re-reads)
static constexpr int kS     = 2048;
static constexpr int kHID   = 2048;
static constexpr int kI     = 4096;
static constexpr int kH     = 64;
static constexpr int kP     = 64;
static constexpr int kN     = 128;
static constexpr int kConv  = 4352;   // I + 2*G*N
static constexpr int kProj  = 8512;   // I + CONV + H  (dt cols included now)
static constexpr int kChunk = 256;
static constexpr int kNC    = 8;
static constexpr float kEps = 1e-5f;

typedef __attribute__((ext_vector_type(8))) short short8;    // 8 x bf16 fragment
typedef __attribute__((ext_vector_type(4))) float floatx4;   // MFMA accumulator

__device__ __forceinline__ float4 f4fma(float a, float4 b, float4 c) {
    c.x += a * b.x; c.y += a * b.y; c.z += a * b.z; c.w += a * b.w; return c;
}
__device__ __forceinline__ float siluf(float x) {
    return x / (1.f + __expf(-x));
}
__device__ __forceinline__ unsigned short f2bf(float f) {   // RNE, finite inputs
    unsigned int u = __float_as_uint(f);
    return (unsigned short)((u + 0x7FFFu + ((u >> 16) & 1u)) >> 16);
}
__device__ __forceinline__ void gll16(const void* g, void* l) {
    __builtin_amdgcn_global_load_lds(
        (const __attribute__((address_space(1))) void*)g,
        (__attribute__((address_space(3))) void*)l, 16, 0, 0);
}

// ---------- fp32 -> bf16 cast, 8 elems/thread ----------
__global__ __launch_bounds__(256)
void cast_bf16_k(const float* __restrict__ in, unsigned short* __restrict__ out)
{
    size_t i = ((size_t)blockIdx.x * 256 + threadIdx.x) * 8;
    float4 a = *(const float4*)&in[i];
    float4 b = *(const float4*)&in[i + 4];
    ushort4 u0 = {f2bf(a.x), f2bf(a.y), f2bf(a.z), f2bf(a.w)};
    ushort4 u1 = {f2bf(b.x), f2bf(b.y), f2bf(b.z), f2bf(b.w)};
    *(ushort4*)&out[i] = u0;
    *(ushort4*)&out[i + 4] = u1;
}

// ---------- bf16 MFMA NT GEMM: C[M,N] = A[M,K] * B[N,K]^T ----------
// 256 thr = 4 waves, tile 128x128, BK=64, mfma_f32_16x16x32_bf16.
// M fixed = 2048 (16 M-tiles). XCD-affinity swizzle: nt ~ (bi&7) mod 8 so the
// 16 M-blocks of one N-column dispatch to ONE XCD -> B-tile L2-resident reuse.
// LDS [row][16B-chunk]: phys = logical ^ (row&7) -> conflict-free frag reads
// AND conflict-free DMA staging (8-lane batches hit 8 distinct bank quads).
// Tail N-tile (N not /128): B row loads clamped, stores guarded.
__global__ __launch_bounds__(256)
void gemm_bt_bf16(const unsigned short* __restrict__ A,
                  const unsigned short* __restrict__ B,
                  float* __restrict__ C, int M, int N, int K)
{
    __shared__ unsigned short As[128 * 64];
    __shared__ unsigned short Bs[128 * 64];
    const int tid = threadIdx.x;
    const int lane = tid & 63, quad = lane >> 4, l15 = lane & 15;
    const int wave = tid >> 6;

    const int Nt = (N + 127) >> 7;
    const int mainN = Nt & ~7;
    int bi = blockIdx.x, mt, nt;
    if (bi < mainN * 16) {
        nt = ((bi >> 7) << 3) | (bi & 7);   // nt % 8 == XCD id (bi % 8)
        mt = (bi >> 3) & 15;                // 16 m-blocks of a column back-to-back
    } else {
        int r = bi - mainN * 16, rem = Nt - mainN;
        nt = mainN + r % rem; mt = r / rem;
    }
    const int m0 = mt * 128, n0 = nt * 128;
    const int wm = (wave & 1) * 64, wn = (wave >> 1) * 64;

    floatx4 acc[4][4] = {};

    // staging coords: f = tid + 256*i -> LDS bytes [f*16, f*16+16): row = f>>3,
    // phys chunk = f&7; source logical chunk = phys ^ (row&7) (same 128B line).
    int rowS[4], lcS[4];
#pragma unroll
    for (int i = 0; i < 4; ++i) {
        int f = tid + 256 * i;
        rowS[i] = f >> 3;
        lcS[i] = ((f & 7) ^ (rowS[i] & 7)) * 8;
    }

    for (int k0 = 0; k0 < K; k0 += 64) {
#pragma unroll
        for (int i = 0; i < 4; ++i) {
            int ra = m0 + rowS[i];
            gll16(&A[(size_t)ra * K + k0 + lcS[i]], &As[(size_t)(tid + 256 * i) * 8]);
        }
#pragma unroll
        for (int i = 0; i < 4; ++i) {
            int rb = n0 + rowS[i]; if (rb > N - 1) rb = N - 1;   // tail clamp
            gll16(&B[(size_t)rb * K + k0 + lcS[i]], &Bs[(size_t)(tid + 256 * i) * 8]);
        }
        __syncthreads();   // compiler drains vmcnt(0) here

        short8 af[4][2], bf[4][2];
#pragma unroll
        for (int ks = 0; ks < 2; ++ks) {
            const int ph = ((ks * 4 + quad) ^ (l15 & 7)) * 8;
#pragma unroll
            for (int mi = 0; mi < 4; ++mi)
                af[mi][ks] = *(const short8*)&As[(size_t)(wm + mi * 16 + l15) * 64 + ph];
#pragma unroll
            for (int ni = 0; ni < 4; ++ni)
                bf[ni][ks] = *(const short8*)&Bs[(size_t)(wn + ni * 16 + l15) * 64 + ph];
        }
#pragma unroll
        for (int ks = 0; ks < 2; ++ks)
#pragma unroll
            for (int mi = 0; mi < 4; ++mi)
#pragma unroll
                for (int ni = 0; ni < 4; ++ni)
                    acc[mi][ni] = __builtin_amdgcn_mfma_f32_16x16x32_bf16(
                        af[mi][ks], bf[ni][ks], acc[mi][ni], 0, 0, 0);
        __syncthreads();
    }

#pragma unroll
    for (int mi = 0; mi < 4; ++mi)
#pragma unroll
        for (int ni = 0; ni < 4; ++ni) {
            int col = n0 + wn + ni * 16 + l15;
            if (col < N) {
#pragma unroll
                for (int r = 0; r < 4; ++r) {
                    int row = m0 + wm + mi * 16 + quad * 4 + r;
                    C[(size_t)row * N + col] = acc[mi][ni][r];
                }
            }
        }
}

// --------------- depthwise causal conv (K=4) + bias + SiLU ------------------
__global__ __launch_bounds__(256)
void conv_silu_k(const float* __restrict__ proj, const float* __restrict__ cw,
                 const float* __restrict__ cb, float* __restrict__ convout)
{
    int idx = blockIdx.x * 256 + threadIdx.x;
    int d = idx % kConv, t = idx / kConv;
    float acc = cb[d];
#pragma unroll
    for (int k = 0; k < 4; ++k) {
        int ts = t + k - 3;
        float u = (ts >= 0) ? proj[(size_t)ts * kProj + kI + d] : 0.f;
        acc += u * cw[d * 4 + k];
    }
    convout[idx] = siluf(acc);
}

// --------------- dt = softplus(proj_dt + bias); per-chunk cumsum(dt*A) ------
// dt_raw now comes from the bf16 proj GEMM (error ~0.007 -> negligible after
// exp decay; see round-5 analysis). One block per (chunk, head), trivial scan.
__global__ __launch_bounds__(256)
void dt_cumsum_k(const float* __restrict__ proj, const float* __restrict__ dt_bias,
                 const float* __restrict__ A_log, float* __restrict__ dt,
                 float* __restrict__ acum)
{
    __shared__ float wsum[4];
    const int c = blockIdx.x >> 6, h = blockIdx.x & 63;
    const int l = threadIdx.x, t = c * kChunk + l;
    float a = -expf(A_log[h]);
    float z = proj[(size_t)t * kProj + kI + kConv + h] + dt_bias[h];
    float d = (z > 20.f) ? z : log1pf(expf(z));
    dt[t * kH + h] = d;
    float v = d * a;
    int lane = l & 63, w = l >> 6;
#pragma unroll
    for (int off = 1; off < 64; off <<= 1) {
        float u = __shfl_up(v, off);
        if (lane >= off) v += u;
    }
    if (lane == 63) wsum[w] = v;
    __syncthreads();
    float add = 0.f;
    for (int i = 0; i < w; ++i) add += wsum[i];
    acum[t * kH + h] = v + add;
}

// --------------- per-chunk end states ---------------------------------------
__global__ __launch_bounds__(256)
void states_k(const float* __restrict__ conv, const float* __restrict__ dt,
              const float* __restrict__ acum, float* __restrict__ states)
{
    __shared__ float Bl[64][132];
    __shared__ float Xl[64][68];
    __shared__ float Wl[64];
    const int c = blockIdx.x >> 6, h = blockIdx.x & 63;
    const int tid = threadIdx.x;
    const int p = tid & 63, ng = tid >> 6;
    const float aend = acum[(size_t)(c * kChunk + 255) * kH + h];
    float4 acc[8];
#pragma unroll
    for (int i = 0; i < 8; ++i) acc[i] = make_float4(0.f, 0.f, 0.f, 0.f);

    for (int lt = 0; lt < 4; ++lt) {
        int tbase = c * kChunk + lt * 64;
#pragma unroll
        for (int r = 0; r < 8; ++r) {
            int f = tid + 256 * r;
            int ll = f >> 5, c4 = (f & 31) * 4;
            *(float4*)&Bl[ll][c4] =
                *(const float4*)&conv[(size_t)(tbase + ll) * kConv + kI + c4];
        }
#pragma unroll
        for (int r = 0; r < 4; ++r) {
            int f = tid + 256 * r;
            int ll = f >> 4, c4 = (f & 15) * 4;
            *(float4*)&Xl[ll][c4] =
                *(const float4*)&conv[(size_t)(tbase + ll) * kConv + h * kP + c4];
        }
        if (tid < 64) {
            int t = tbase + tid;
            Wl[tid] = __expf(aend - acum[(size_t)t * kH + h]) * dt[(size_t)t * kH + h];
        }
        __syncthreads();
        for (int ll = 0; ll < 64; ++ll) {
            float xv = Xl[ll][p] * Wl[ll];
#pragma unroll
            for (int j = 0; j < 8; ++j) {
                float4 b = *(const float4*)&Bl[ll][ng * 32 + j * 4];
                acc[j] = f4fma(xv, b, acc[j]);
            }
        }
        __syncthreads();
    }
    size_t base = ((size_t)(c * kH + h) * kP + p) * kN + ng * 32;
#pragma unroll
    for (int j = 0; j < 8; ++j) *(float4*)&states[base + j * 4] = acc[j];
}

// --------------- sequential inter-chunk recurrence (8 chunks) ---------------
__global__ __launch_bounds__(256)
void scan_k(const float* __restrict__ states, const float* __restrict__ acum,
            float* __restrict__ prev)
{
    const int h = blockIdx.x >> 3, seg = blockIdx.x & 7;
    const int e = (seg * 256 + threadIdx.x) * 4;
    float4 carry = make_float4(0.f, 0.f, 0.f, 0.f);
    for (int c = 0; c < kNC; ++c) {
        size_t base = (size_t)(c * kH + h) * (kP * kN);
        *(float4*)&prev[base + e] = carry;
        float dec = __expf(acum[(size_t)(c * kChunk + 255) * kH + h]);
        float4 st = *(const float4*)&states[base + e];
        carry.x = carry.x * dec + st.x; carry.y = carry.y * dec + st.y;
        carry.z = carry.z * dec + st.z; carry.w = carry.w * dec + st.w;
    }
}

// --------------- SSD Y (v3): bf16 MFMA flash-style --------------------------
__global__ __launch_bounds__(256)
void ssd_y3_k(const float* __restrict__ conv, const float* __restrict__ dt,
              const float* __restrict__ acum, const float* __restrict__ prev,
              const float* __restrict__ Dp, float* __restrict__ Y)
{
    __shared__ unsigned short Cb[64 * 136];  // C[t][n]
    __shared__ unsigned short Bb[64 * 136];  // prev[p][n], then B[s][n] per si
    __shared__ unsigned short Xt[64 * 72];   // X^T [p][s] per si
    __shared__ unsigned short Wb[64 * 72];   // W [t][s] (wave-private strips)
    __shared__ float At[64], Asv[64], Dtv[64];

    const int bi = blockIdx.x;
    const int ti = bi & 3, h = (bi >> 2) & 63, c = bi >> 8;
    const int tid = threadIdx.x;
    const int wave = tid >> 6, lane = tid & 63;
    const int quad = lane >> 4, l15 = lane & 15;
    const int trow0 = c * kChunk + ti * 64;
    const float Dh = Dp[h];

#pragma unroll
    for (int r = 0; r < 8; ++r) {
        int f = tid + 256 * r;
        int row = f >> 5, c4 = (f & 31) * 4;
        float4 v = *(const float4*)&conv[(size_t)(trow0 + row) * kConv + kI + kN + c4];
        ushort4 u = {f2bf(v.x), f2bf(v.y), f2bf(v.z), f2bf(v.w)};
        *(ushort4*)&Cb[row * 136 + c4] = u;
    }
    const size_t pbase = (size_t)(c * kH + h) * (kP * kN);
#pragma unroll
    for (int r = 0; r < 8; ++r) {
        int f = tid + 256 * r;
        int row = f >> 5, c4 = (f & 31) * 4;
        float4 v = *(const float4*)&prev[pbase + (size_t)row * kN + c4];
        ushort4 u = {f2bf(v.x), f2bf(v.y), f2bf(v.z), f2bf(v.w)};
        *(ushort4*)&Bb[row * 136 + c4] = u;
    }
    if (tid < 64) At[tid] = acum[(size_t)(trow0 + tid) * kH + h];
    __syncthreads();

    floatx4 yacc[4] = {};
#pragma unroll
    for (int ks = 0; ks < 4; ++ks) {
        short8 a = *(const short8*)&Cb[(wave * 16 + l15) * 136 + ks * 32 + quad * 8];
#pragma unroll
        for (int ni = 0; ni < 4; ++ni) {
            short8 b = *(const short8*)&Bb[(ni * 16 + l15) * 136 + ks * 32 + quad * 8];
            yacc[ni] = __builtin_amdgcn_mfma_f32_16x16x32_bf16(a, b, yacc[ni], 0, 0, 0);
        }
    }
    {
        float eAr[4];
#pragma unroll
        for (int r = 0; r < 4; ++r) eAr[r] = __expf(At[wave * 16 + quad * 4 + r]);
#pragma unroll
        for (int ni = 0; ni < 4; ++ni)
#pragma unroll
            for (int r = 0; r < 4; ++r) yacc[ni][r] *= eAr[r];
    }

    for (int si = 0; si <= ti; ++si) {
        const int srow0 = c * kChunk + si * 64;
        __syncthreads();
#pragma unroll
        for (int r = 0; r < 8; ++r) {
            int f = tid + 256 * r;
            int row = f >> 5, c4 = (f & 31) * 4;
            float4 v = *(const float4*)&conv[(size_t)(srow0 + row) * kConv + kI + c4];
            ushort4 u = {f2bf(v.x), f2bf(v.y), f2bf(v.z), f2bf(v.w)};
            *(ushort4*)&Bb[row * 136 + c4] = u;
        }
#pragma unroll
        for (int it = 0; it < 2; ++it) {
            int f = tid + 256 * it;
            int p = f & 63, sb = (f >> 6) * 8;
            float vs[8];
#pragma unroll
            for (int j = 0; j < 8; ++j)
                vs[j] = conv[(size_t)(srow0 + sb + j) * kConv + h * kP + p];
            ushort4 u0 = {f2bf(vs[0]), f2bf(vs[1]), f2bf(vs[2]), f2bf(vs[3])};
            ushort4 u1 = {f2bf(vs[4]), f2bf(vs[5]), f2bf(vs[6]), f2bf(vs[7])};
            *(ushort4*)&Xt[p * 72 + sb] = u0;
            *(ushort4*)&Xt[p * 72 + sb + 4] = u1;
        }
        if (tid < 64) {
            Asv[tid] = acum[(size_t)(srow0 + tid) * kH + h];
            Dtv[tid] = dt[(size_t)(srow0 + tid) * kH + h];
        }
        __syncthreads();

        floatx4 sacc[4] = {};
#pragma unroll
        for (int ks = 0; ks < 4; ++ks) {
            short8 a = *(const short8*)&Cb[(wave * 16 + l15) * 136 + ks * 32 + quad * 8];
#pragma unroll
            for (int ni = 0; ni < 4; ++ni) {
                short8 b = *(const short8*)&Bb[(ni * 16 + l15) * 136 + ks * 32 + quad * 8];
                sacc[ni] = __builtin_amdgcn_mfma_f32_16x16x32_bf16(a, b, sacc[ni], 0, 0, 0);
            }
        }

        const bool diag = (si == ti);
#pragma unroll
        for (int ni = 0; ni < 4; ++ni) {
            int s_ = ni * 16 + l15;
            float as = Asv[s_], dts = Dtv[s_];
#pragma unroll
            for (int r = 0; r < 4; ++r) {
                int tl = wave * 16 + quad * 4 + r;
                float w = sacc[ni][r] * __expf(At[tl] - as) * dts;
                if (diag) {
                    if (s_ > tl) w = 0.f;
                    else if (s_ == tl) w += Dh;
                }
                Wb[tl * 72 + s_] = f2bf(w);
            }
        }
#pragma unroll
        for (int ks = 0; ks < 2; ++ks) {
            short8 aw = *(const short8*)&Wb[(wave * 16 + l15) * 72 + ks * 32 + quad * 8];
#pragma unroll
            for (int ni = 0; ni < 4; ++ni) {
                short8 xb = *(const short8*)&Xt[(ni * 16 + l15) * 72 + ks * 32 + quad * 8];
                yacc[ni] = __builtin_amdgcn_mfma_f32_16x16x32_bf16(aw, xb, yacc[ni], 0, 0, 0);
            }
        }
    }

#pragma unroll
    for (int ni = 0; ni < 4; ++ni)
#pragma unroll
        for (int r = 0; r < 4; ++r)
            Y[(size_t)(trow0 + wave * 16 + quad * 4 + r) * kI + h * kP + ni * 16 + l15]
                = yacc[ni][r];
}

// --------------- gated RMSNorm -> bf16 output for final MFMA GEMM -----------
__global__ __launch_bounds__(256)
void rmsnorm_gate_k(const float* __restrict__ Y, const float* __restrict__ proj,
                    const float* __restrict__ nw, unsigned short* __restrict__ Yb)
{
    __shared__ float red[4];
    const int t = blockIdx.x, tid = threadIdx.x;
    const float* yrow = &Y[(size_t)t * kI];
    const float* grow = &proj[(size_t)t * kProj];
    float v[16];
    float ss = 0.f;
#pragma unroll
    for (int j = 0; j < 4; ++j) {
        int i = (tid + 256 * j) * 4;
        float4 y4 = *(const float4*)&yrow[i];
        float4 g4 = *(const float4*)&grow[i];
        float a = y4.x * siluf(g4.x), bq = y4.y * siluf(g4.y);
        float cq = y4.z * siluf(g4.z), d = y4.w * siluf(g4.w);
        v[j * 4 + 0] = a; v[j * 4 + 1] = bq; v[j * 4 + 2] = cq; v[j * 4 + 3] = d;
        ss += a * a + bq * bq + cq * cq + d * d;
    }
#pragma unroll
    for (int off = 32; off > 0; off >>= 1) ss += __shfl_down(ss, off);
    if ((tid & 63) == 0) red[tid >> 6] = ss;
    __syncthreads();
    float sum = red[0] + red[1] + red[2] + red[3];
    float rr = rsqrtf(sum * (1.f / kI) + kEps);
#pragma unroll
    for (int j = 0; j < 4; ++j) {
        int i = (tid + 256 * j) * 4;
        float4 w4 = *(const float4*)&nw[i];
        ushort4 o;
        o.x = f2bf(v[j * 4 + 0] * rr * w4.x);
        o.y = f2bf(v[j * 4 + 1] * rr * w4.y);
        o.z = f2bf(v[j * 4 + 2] * rr * w4.z);
        o.w = f2bf(v[j * 4 + 3] * rr * w4.w);
        *(ushort4*)&Yb[(size_t)t * kI + i] = o;
    }
}

extern "C" void kernel_launch(void* const* d_in, const int* in_sizes, int n_in,
                              void* d_out, int out_size, void* d_ws, size_t ws_size,
                              hipStream_t stream)
{
    const float* x       = (const float*)d_in[0];
    const float* W_in    = (const float*)d_in[1];
    const float* conv_w  = (const float*)d_in[2];
    const float* conv_b  = (const float*)d_in[3];
    const float* dt_bias = (const float*)d_in[4];
    const float* A_log   = (const float*)d_in[5];
    const float* Dp      = (const float*)d_in[6];
    const float* norm_w  = (const float*)d_in[7];
    const float* W_out   = (const float*)d_in[8];
    float* out = (float*)d_out;

    // workspace (floats), ~156.8 MB (== round-1 footprint), aliasing timeline:
    // R1: Wb(cast->projGEMM) -> prev + Y/states -> Yb(after ssd_y3)
    // conv region: xb (early) ... conv ... Wob (after ssd_y3)
    float* ws   = (float*)d_ws;
    float* proj = ws;                                    // 2048*8512
    float* conv = proj + (size_t)kS * kProj;             // 2048*4352
    float* dtb  = conv + (size_t)kS * kConv;             // 2048*64
    float* acum = dtb + (size_t)kS * kH;                 // 2048*64
    float* R1   = acum + (size_t)kS * kH;                // 12,582,912 floats
    float* prev   = R1;                                  // 4,194,304
    float* Y      = R1 + (size_t)kNC * kH * kP * kN;     // 8,388,608
    float* states = Y;
    unsigned short* Wb  = (unsigned short*)R1;           // 8512*2048 bf16 (early)
    unsigned short* Yb  = (unsigned short*)R1;           // 2048*4096 bf16 (late)
    unsigned short* xb  = (unsigned short*)conv;         // 2048*2048 bf16 (early)
    unsigned short* Wob = (unsigned short*)conv;         // 2048*4096 bf16 (late)

    dim3 blk(256);
    const int NtP = (kProj + 127) / 128;   // 67 (tail tile guarded in-kernel)
    const int NtO = kHID / 128;            // 16
    cast_bf16_k<<<(kS * kHID) / 2048, blk, 0, stream>>>(x, xb);
    cast_bf16_k<<<(kProj * kHID) / 2048, blk, 0, stream>>>(W_in, Wb);
    gemm_bt_bf16<<<NtP * 16, blk, 0, stream>>>(xb, Wb, proj, kS, kProj, kHID);
    conv_silu_k<<<(kS * kConv) / 256, blk, 0, stream>>>(proj, conv_w, conv_b, conv);
    dt_cumsum_k<<<kNC * kH, blk, 0, stream>>>(proj, dt_bias, A_log, dtb, acum);
    states_k<<<kNC * kH, blk, 0, stream>>>(conv, dtb, acum, states);
    scan_k<<<kH * 8, blk, 0, stream>>>(states, acum, prev);
    ssd_y3_k<<<kNC * kH * 4, blk, 0, stream>>>(conv, dtb, acum, prev, Dp, Y);
    rmsnorm_gate_k<<<kS, blk, 0, stream>>>(Y, proj, norm_w, Yb);
    cast_bf16_k<<<(kHID * kI) / 2048, blk, 0, stream>>>(W_out, Wob);
    gemm_bt_bf16<<<NtO * 16, blk, 0, stream>>>(Yb, Wob, out, kS, kHID, kI);
}

// Round 8
// 492.135 us; speedup vs baseline: 7.0258x; 1.0637x over previous
//
#include <hip/hip_runtime.h>
#include <math.h>

// Bamba-9B mixer, b=1 s=2048. Round 7 (resubmit; round-7 bench was an infra
// timeout): mid-pipeline bf16-ification.
//  - conv_silu2 writes bf16 in consumer layouts (XT[i][s], Bg[s][n], Bt[n][s],
//    Cg[s][n]); fp32 conv array deleted.
//  - states2: bf16 MFMA (Xw^T . Bt), gll16 staging, XOR-swizzled LDS.
//  - ssd_y4: all tiles gll16-staged from bf16 layouts; no per-elem f2bf.
// GEMMs unchanged (m97-structure plateau at this shape; next round = MX-fp8
// or restructured K-loop).
static constexpr int kS     = 2048;
static constexpr int kHID   = 2048;
static constexpr int kI     = 4096;
static constexpr int kH     = 64;
static constexpr int kP     = 64;
static constexpr int kN     = 128;
static constexpr int kConv  = 4352;   // I + 2*G*N
static constexpr int kProj  = 8512;   // I + CONV + H
static constexpr int kChunk = 256;
static constexpr int kNC    = 8;
static constexpr float kEps = 1e-5f;

typedef __attribute__((ext_vector_type(8))) short short8;            // bf16 frag
typedef __attribute__((ext_vector_type(8))) unsigned short ushort8v;
typedef __attribute__((ext_vector_type(4))) float floatx4;

__device__ __forceinline__ float siluf(float x) {
    return x / (1.f + __expf(-x));
}
__device__ __forceinline__ unsigned short f2bf(float f) {   // RNE, finite
    unsigned int u = __float_as_uint(f);
    return (unsigned short)((u + 0x7FFFu + ((u >> 16) & 1u)) >> 16);
}
__device__ __forceinline__ float bf2f(unsigned short u) {
    return __uint_as_float((unsigned int)u << 16);
}
__device__ __forceinline__ void gll16(const void* g, void* l) {
    __builtin_amdgcn_global_load_lds(
        (const __attribute__((address_space(1))) void*)g,
        (__attribute__((address_space(3))) void*)l, 16, 0, 0);
}

// ---------- fp32 -> bf16 cast, 8 elems/thread ----------
__global__ __launch_bounds__(256)
void cast_bf16_k(const float* __restrict__ in, unsigned short* __restrict__ out)
{
    size_t i = ((size_t)blockIdx.x * 256 + threadIdx.x) * 8;
    float4 a = *(const float4*)&in[i];
    float4 b = *(const float4*)&in[i + 4];
    ushort4 u0 = {f2bf(a.x), f2bf(a.y), f2bf(a.z), f2bf(a.w)};
    ushort4 u1 = {f2bf(b.x), f2bf(b.y), f2bf(b.z), f2bf(b.w)};
    *(ushort4*)&out[i] = u0;
    *(ushort4*)&out[i + 4] = u1;
}

// ---------- bf16 MFMA NT GEMM (unchanged from round 5) ----------
__global__ __launch_bounds__(256)
void gemm_bt_bf16(const unsigned short* __restrict__ A,
                  const unsigned short* __restrict__ B,
                  float* __restrict__ C, int M, int N, int K)
{
    __shared__ unsigned short As[128 * 64];
    __shared__ unsigned short Bs[128 * 64];
    const int tid = threadIdx.x;
    const int lane = tid & 63, quad = lane >> 4, l15 = lane & 15;
    const int wave = tid >> 6;

    const int Nt = (N + 127) >> 7;
    const int mainN = Nt & ~7;
    int bi = blockIdx.x, mt, nt;
    if (bi < mainN * 16) {
        nt = ((bi >> 7) << 3) | (bi & 7);
        mt = (bi >> 3) & 15;
    } else {
        int r = bi - mainN * 16, rem = Nt - mainN;
        nt = mainN + r % rem; mt = r / rem;
    }
    const int m0 = mt * 128, n0 = nt * 128;
    const int wm = (wave & 1) * 64, wn = (wave >> 1) * 64;

    floatx4 acc[4][4] = {};

    int rowS[4], lcS[4];
#pragma unroll
    for (int i = 0; i < 4; ++i) {
        int f = tid + 256 * i;
        rowS[i] = f >> 3;
        lcS[i] = ((f & 7) ^ (rowS[i] & 7)) * 8;
    }

    for (int k0 = 0; k0 < K; k0 += 64) {
#pragma unroll
        for (int i = 0; i < 4; ++i) {
            int ra = m0 + rowS[i];
            gll16(&A[(size_t)ra * K + k0 + lcS[i]], &As[(size_t)(tid + 256 * i) * 8]);
        }
#pragma unroll
        for (int i = 0; i < 4; ++i) {
            int rb = n0 + rowS[i]; if (rb > N - 1) rb = N - 1;
            gll16(&B[(size_t)rb * K + k0 + lcS[i]], &Bs[(size_t)(tid + 256 * i) * 8]);
        }
        __syncthreads();

        short8 af[4][2], bf[4][2];
#pragma unroll
        for (int ks = 0; ks < 2; ++ks) {
            const int ph = ((ks * 4 + quad) ^ (l15 & 7)) * 8;
#pragma unroll
            for (int mi = 0; mi < 4; ++mi)
                af[mi][ks] = *(const short8*)&As[(size_t)(wm + mi * 16 + l15) * 64 + ph];
#pragma unroll
            for (int ni = 0; ni < 4; ++ni)
                bf[ni][ks] = *(const short8*)&Bs[(size_t)(wn + ni * 16 + l15) * 64 + ph];
        }
#pragma unroll
        for (int ks = 0; ks < 2; ++ks)
#pragma unroll
            for (int mi = 0; mi < 4; ++mi)
#pragma unroll
                for (int ni = 0; ni < 4; ++ni)
                    acc[mi][ni] = __builtin_amdgcn_mfma_f32_16x16x32_bf16(
                        af[mi][ks], bf[ni][ks], acc[mi][ni], 0, 0, 0);
        __syncthreads();
    }

#pragma unroll
    for (int mi = 0; mi < 4; ++mi)
#pragma unroll
        for (int ni = 0; ni < 4; ++ni) {
            int col = n0 + wn + ni * 16 + l15;
            if (col < N) {
#pragma unroll
                for (int r = 0; r < 4; ++r) {
                    int row = m0 + wm + mi * 16 + quad * 4 + r;
                    C[(size_t)row * N + col] = acc[mi][ni][r];
                }
            }
        }
}

// ---------- conv+SiLU -> bf16 consumer layouts ----------
// block = (d-tile 64, t-tile 256). LDS transpose buffer T[d][t].
// d<4096: write XT[i=d][s];  4096<=d<4224: Bg[s][n] + Bt[n][s];  else Cg[s][n].
__global__ __launch_bounds__(256)
void conv_silu2_k(const float* __restrict__ proj, const float* __restrict__ cw,
                  const float* __restrict__ cb,
                  unsigned short* __restrict__ XT, unsigned short* __restrict__ Bg,
                  unsigned short* __restrict__ Btg, unsigned short* __restrict__ Cg)
{
    __shared__ __attribute__((aligned(16))) unsigned short T[64][264];
    const int bd = blockIdx.x % 68, bt = blockIdx.x / 68;
    const int d0 = bd * 64, t0 = bt * 256;
    const int tid = threadIdx.x;
    const int dl = tid & 63;
    const int d = d0 + dl;
    const float b0 = cb[d];
    const float w0 = cw[d * 4 + 0], w1 = cw[d * 4 + 1];
    const float w2 = cw[d * 4 + 2], w3 = cw[d * 4 + 3];
    for (int it = 0; it < 64; ++it) {
        int tl = it * 4 + (tid >> 6);
        int t = t0 + tl;
        const float* pc = &proj[(size_t)t * kProj + kI + d];
        float acc = b0 + w3 * pc[0];
        if (t >= 1) acc += w2 * pc[-(ptrdiff_t)kProj];
        if (t >= 2) acc += w1 * pc[-(ptrdiff_t)(2 * kProj)];
        if (t >= 3) acc += w0 * pc[-(ptrdiff_t)(3 * kProj)];
        T[dl][tl] = f2bf(siluf(acc));
    }
    __syncthreads();

    if (d0 < kI) {                       // X: XT[d][t], rows along t (coalesced)
        int row = tid >> 2, cg = (tid & 3) * 64;
#pragma unroll
        for (int j = 0; j < 8; ++j)
            *(ushort8v*)&XT[(size_t)(d0 + row) * kS + t0 + cg + j * 8] =
                *(const ushort8v*)&T[row][cg + j * 8];
    } else if (d0 < kI + kN) {           // B: Bt[n][t] + Bg[t][n]
        int n0 = d0 - kI;
        int row = tid >> 2, cg = (tid & 3) * 64;
#pragma unroll
        for (int j = 0; j < 8; ++j)
            *(ushort8v*)&Btg[(size_t)(n0 + row) * kS + t0 + cg + j * 8] =
                *(const ushort8v*)&T[row][cg + j * 8];
        for (int pass = 0; pass < 16; ++pass) {
            int tl = pass * 16 + (tid >> 4), nq = (tid & 15) * 4;
            ushort4 v = {T[nq][tl], T[nq + 1][tl], T[nq + 2][tl], T[nq + 3][tl]};
            *(ushort4*)&Bg[(size_t)(t0 + tl) * kN + n0 + nq] = v;
        }
    } else {                             // C: Cg[t][n]
        int n0 = d0 - (kI + kN);
        for (int pass = 0; pass < 16; ++pass) {
            int tl = pass * 16 + (tid >> 4), nq = (tid & 15) * 4;
            ushort4 v = {T[nq][tl], T[nq + 1][tl], T[nq + 2][tl], T[nq + 3][tl]};
            *(ushort4*)&Cg[(size_t)(t0 + tl) * kN + n0 + nq] = v;
        }
    }
}

// ---------- dt = softplus(proj_dt + bias); per-chunk cumsum(dt*A) ----------
__global__ __launch_bounds__(256)
void dt_cumsum_k(const float* __restrict__ proj, const float* __restrict__ dt_bias,
                 const float* __restrict__ A_log, float* __restrict__ dt,
                 float* __restrict__ acum)
{
    __shared__ float wsum[4];
    const int c = blockIdx.x >> 6, h = blockIdx.x & 63;
    const int l = threadIdx.x, t = c * kChunk + l;
    float a = -expf(A_log[h]);
    float z = proj[(size_t)t * kProj + kI + kConv + h] + dt_bias[h];
    float d = (z > 20.f) ? z : log1pf(expf(z));
    dt[t * kH + h] = d;
    float v = d * a;
    int lane = l & 63, w = l >> 6;
#pragma unroll
    for (int off = 1; off < 64; off <<= 1) {
        float u = __shfl_up(v, off);
        if (lane >= off) v += u;
    }
    if (lane == 63) wsum[w] = v;
    __syncthreads();
    float add = 0.f;
    for (int i = 0; i < w; ++i) add += wsum[i];
    acum[t * kH + h] = v + add;
}

// ---------- states (v2): bf16 MFMA. out[p][n] = sum_s Xw^T[p][s] Bt[n][s] ---
// block = (c,h). Aw staged manually (w folded), Bt via gll16 + XOR swizzle.
__global__ __launch_bounds__(256)
void states2_k(const unsigned short* __restrict__ XT,
               const unsigned short* __restrict__ Btg,
               const float* __restrict__ dt, const float* __restrict__ acum,
               float* __restrict__ states)
{
    __shared__ __attribute__((aligned(16))) unsigned short Aw[64 * 72];
    __shared__ __attribute__((aligned(16))) unsigned short Bs[128 * 64];
    __shared__ float Wl[256];
    const int c = blockIdx.x >> 6, h = blockIdx.x & 63;
    const int tid = threadIdx.x;
    const int wave = tid >> 6, lane = tid & 63;
    const int quad = lane >> 4, l15 = lane & 15;
    const float aend = acum[(size_t)(c * kChunk + 255) * kH + h];
    {
        int t = c * kChunk + tid;
        Wl[tid] = __expf(aend - acum[(size_t)t * kH + h]) * dt[(size_t)t * kH + h];
    }
    __syncthreads();

    floatx4 acc[4][2] = {};
    for (int lt = 0; lt < 4; ++lt) {
        const int s0 = c * kChunk + lt * 64;
#pragma unroll
        for (int i = 0; i < 2; ++i) {       // Aw[p][s] = XT * w, stride 72
            int f = tid + 256 * i;
            int p = f >> 3, sc = (f & 7) * 8;
            ushort8v xv = *(const ushort8v*)&XT[(size_t)(h * 64 + p) * kS + s0 + sc];
            ushort8v o;
#pragma unroll
            for (int j = 0; j < 8; ++j)
                o[j] = f2bf(bf2f(xv[j]) * Wl[lt * 64 + sc + j]);
            *(ushort8v*)&Aw[p * 72 + sc] = o;
        }
#pragma unroll
        for (int i = 0; i < 4; ++i) {       // Bs[n][s], phys chunk = lg ^ (n&7)
            int f = tid + 256 * i;
            int n = f >> 3, ph = f & 7, lg = ph ^ (n & 7);
            gll16(&Btg[(size_t)n * kS + s0 + lg * 8], &Bs[(size_t)f * 8]);
        }
        __syncthreads();
#pragma unroll
        for (int ks = 0; ks < 2; ++ks) {
            short8 bfr[2];
#pragma unroll
            for (int nj = 0; nj < 2; ++nj) {
                int n = (wave * 2 + nj) * 16 + l15;
                int ph = (ks * 4 + quad) ^ (n & 7);
                bfr[nj] = *(const short8*)&Bs[n * 64 + ph * 8];
            }
#pragma unroll
            for (int pi = 0; pi < 4; ++pi) {
                short8 af = *(const short8*)&Aw[(pi * 16 + l15) * 72 + ks * 32 + quad * 8];
                acc[pi][0] = __builtin_amdgcn_mfma_f32_16x16x32_bf16(af, bfr[0], acc[pi][0], 0, 0, 0);
                acc[pi][1] = __builtin_amdgcn_mfma_f32_16x16x32_bf16(af, bfr[1], acc[pi][1], 0, 0, 0);
            }
        }
        __syncthreads();
    }
    const size_t base = (size_t)(c * kH + h) * (kP * kN);
#pragma unroll
    for (int pi = 0; pi < 4; ++pi)
#pragma unroll
        for (int nj = 0; nj < 2; ++nj) {
            int n = (wave * 2 + nj) * 16 + l15;
#pragma unroll
            for (int r = 0; r < 4; ++r)
                states[base + (size_t)(pi * 16 + quad * 4 + r) * kN + n] = acc[pi][nj][r];
        }
}

// ---------- sequential inter-chunk recurrence ----------
__global__ __launch_bounds__(256)
void scan_k(const float* __restrict__ states, const float* __restrict__ acum,
            float* __restrict__ prev)
{
    const int h = blockIdx.x >> 3, seg = blockIdx.x & 7;
    const int e = (seg * 256 + threadIdx.x) * 4;
    float4 carry = make_float4(0.f, 0.f, 0.f, 0.f);
    for (int c = 0; c < kNC; ++c) {
        size_t base = (size_t)(c * kH + h) * (kP * kN);
        *(float4*)&prev[base + e] = carry;
        float dec = __expf(acum[(size_t)(c * kChunk + 255) * kH + h]);
        float4 st = *(const float4*)&states[base + e];
        carry.x = carry.x * dec + st.x; carry.y = carry.y * dec + st.y;
        carry.z = carry.z * dec + st.z; carry.w = carry.w * dec + st.w;
    }
}

// ---------- SSD Y (v4): gll16-staged bf16 tiles, XOR-swizzled ----------
// Cb/Bb [row][n] stride 128, phys16 = ch ^ (row&15); Xt [p][s] stride 64,
// phys8 = ch ^ (p&7); Wb [t][s] stride 72 (pad). LDS ~50 KB.
__global__ __launch_bounds__(256)
void ssd_y4_k(const unsigned short* __restrict__ Cg,
              const unsigned short* __restrict__ Bg,
              const unsigned short* __restrict__ XT,
              const float* __restrict__ dt, const float* __restrict__ acum,
              const float* __restrict__ prev, const float* __restrict__ Dp,
              float* __restrict__ Y)
{
    __shared__ __attribute__((aligned(16))) unsigned short Cb[64 * 128];
    __shared__ __attribute__((aligned(16))) unsigned short Bb[64 * 128];
    __shared__ __attribute__((aligned(16))) unsigned short Xt[64 * 64];
    __shared__ __attribute__((aligned(16))) unsigned short Wb[64 * 72];
    __shared__ float At[64], Asv[64], Dtv[64];

    const int bi = blockIdx.x;
    const int ti = bi & 3, h = (bi >> 2) & 63, c = bi >> 8;
    const int tid = threadIdx.x;
    const int wave = tid >> 6, lane = tid & 63;
    const int quad = lane >> 4, l15 = lane & 15;
    const int trow0 = c * kChunk + ti * 64;
    const float Dh = Dp[h];

    // stage C tile (gll16) + prev tile (fp32 -> bf16, swizzled manual write)
#pragma unroll
    for (int i = 0; i < 4; ++i) {
        int f = tid + 256 * i;
        int row = f >> 4, ph = f & 15, lg = ph ^ (row & 15);
        gll16(&Cg[(size_t)(trow0 + row) * kN + lg * 8], &Cb[(size_t)f * 8]);
    }
    const size_t pbase = (size_t)(c * kH + h) * (kP * kN);
#pragma unroll
    for (int r = 0; r < 8; ++r) {
        int f = tid + 256 * r;
        int row = f >> 5, c4 = (f & 31) * 4;          // 4 fp32 = half a 16B chunk
        float4 v = *(const float4*)&prev[pbase + (size_t)row * kN + c4];
        ushort4 u = {f2bf(v.x), f2bf(v.y), f2bf(v.z), f2bf(v.w)};
        int dst = row * 128 + ((((f & 31) >> 1) ^ (row & 15)) * 8) + (f & 1) * 4;
        *(ushort4*)&Bb[dst] = u;
    }
    if (tid < 64) At[tid] = acum[(size_t)(trow0 + tid) * kH + h];
    __syncthreads();

    // inter-chunk: yacc = C . prev^T  (K=128)
    floatx4 yacc[4] = {};
#pragma unroll
    for (int ks = 0; ks < 4; ++ks) {
        int cha = (ks * 4 + quad) ^ l15;
        short8 a = *(const short8*)&Cb[(wave * 16 + l15) * 128 + cha * 8];
#pragma unroll
        for (int ni = 0; ni < 4; ++ni) {
            short8 b = *(const short8*)&Bb[(ni * 16 + l15) * 128 + cha * 8];
            yacc[ni] = __builtin_amdgcn_mfma_f32_16x16x32_bf16(a, b, yacc[ni], 0, 0, 0);
        }
    }
    {
        float eAr[4];
#pragma unroll
        for (int r = 0; r < 4; ++r) eAr[r] = __expf(At[wave * 16 + quad * 4 + r]);
#pragma unroll
        for (int ni = 0; ni < 4; ++ni)
#pragma unroll
            for (int r = 0; r < 4; ++r) yacc[ni][r] *= eAr[r];
    }

    for (int si = 0; si <= ti; ++si) {
        const int srow0 = c * kChunk + si * 64;
        __syncthreads();
#pragma unroll
        for (int i = 0; i < 4; ++i) {       // B tile
            int f = tid + 256 * i;
            int row = f >> 4, ph = f & 15, lg = ph ^ (row & 15);
            gll16(&Bg[(size_t)(srow0 + row) * kN + lg * 8], &Bb[(size_t)f * 8]);
        }
#pragma unroll
        for (int i = 0; i < 2; ++i) {       // X^T tile [p][s]
            int f = tid + 256 * i;
            int p = f >> 3, ph = f & 7, lg = ph ^ (p & 7);
            gll16(&XT[(size_t)(h * 64 + p) * kS + srow0 + lg * 8], &Xt[(size_t)f * 8]);
        }
        if (tid < 64) {
            Asv[tid] = acum[(size_t)(srow0 + tid) * kH + h];
            Dtv[tid] = dt[(size_t)(srow0 + tid) * kH + h];
        }
        __syncthreads();

        // S = C . B^T  (K=128)
        floatx4 sacc[4] = {};
#pragma unroll
        for (int ks = 0; ks < 4; ++ks) {
            int cha = (ks * 4 + quad) ^ l15;
            short8 a = *(const short8*)&Cb[(wave * 16 + l15) * 128 + cha * 8];
#pragma unroll
            for (int ni = 0; ni < 4; ++ni) {
                short8 b = *(const short8*)&Bb[(ni * 16 + l15) * 128 + cha * 8];
                sacc[ni] = __builtin_amdgcn_mfma_f32_16x16x32_bf16(a, b, sacc[ni], 0, 0, 0);
            }
        }

        // weight (fp32) -> Wb[t][s] bf16; D folded into diagonal
        const bool diag = (si == ti);
#pragma unroll
        for (int ni = 0; ni < 4; ++ni) {
            int s_ = ni * 16 + l15;
            float as = Asv[s_], dts = Dtv[s_];
#pragma unroll
            for (int r = 0; r < 4; ++r) {
                int tl = wave * 16 + quad * 4 + r;
                float w = sacc[ni][r] * __expf(At[tl] - as) * dts;
                if (diag) {
                    if (s_ > tl) w = 0.f;
                    else if (s_ == tl) w += Dh;
                }
                Wb[tl * 72 + s_] = f2bf(w);
            }
        }
        // Y += W . X^T  (K=64); same-wave LDS write->read on Wb strip
#pragma unroll
        for (int ks = 0; ks < 2; ++ks) {
            short8 aw = *(const short8*)&Wb[(wave * 16 + l15) * 72 + ks * 32 + quad * 8];
#pragma unroll
            for (int ni = 0; ni < 4; ++ni) {
                int ph = ((ks * 4 + quad) ^ (l15 & 7)) * 8;
                short8 xb = *(const short8*)&Xt[(ni * 16 + l15) * 64 + ph];
                yacc[ni] = __builtin_amdgcn_mfma_f32_16x16x32_bf16(aw, xb, yacc[ni], 0, 0, 0);
            }
        }
    }

#pragma unroll
    for (int ni = 0; ni < 4; ++ni)
#pragma unroll
        for (int r = 0; r < 4; ++r)
            Y[(size_t)(trow0 + wave * 16 + quad * 4 + r) * kI + h * kP + ni * 16 + l15]
                = yacc[ni][r];
}

// ---------- gated RMSNorm -> bf16 ----------
__global__ __launch_bounds__(256)
void rmsnorm_gate_k(const float* __restrict__ Y, const float* __restrict__ proj,
                    const float* __restrict__ nw, unsigned short* __restrict__ Yb)
{
    __shared__ float red[4];
    const int t = blockIdx.x, tid = threadIdx.x;
    const float* yrow = &Y[(size_t)t * kI];
    const float* grow = &proj[(size_t)t * kProj];
    float v[16];
    float ss = 0.f;
#pragma unroll
    for (int j = 0; j < 4; ++j) {
        int i = (tid + 256 * j) * 4;
        float4 y4 = *(const float4*)&yrow[i];
        float4 g4 = *(const float4*)&grow[i];
        float a = y4.x * siluf(g4.x), bq = y4.y * siluf(g4.y);
        float cq = y4.z * siluf(g4.z), d = y4.w * siluf(g4.w);
        v[j * 4 + 0] = a; v[j * 4 + 1] = bq; v[j * 4 + 2] = cq; v[j * 4 + 3] = d;
        ss += a * a + bq * bq + cq * cq + d * d;
    }
#pragma unroll
    for (int off = 32; off > 0; off >>= 1) ss += __shfl_down(ss, off);
    if ((tid & 63) == 0) red[tid >> 6] = ss;
    __syncthreads();
    float sum = red[0] + red[1] + red[2] + red[3];
    float rr = rsqrtf(sum * (1.f / kI) + kEps);
#pragma unroll
    for (int j = 0; j < 4; ++j) {
        int i = (tid + 256 * j) * 4;
        float4 w4 = *(const float4*)&nw[i];
        ushort4 o;
        o.x = f2bf(v[j * 4 + 0] * rr * w4.x);
        o.y = f2bf(v[j * 4 + 1] * rr * w4.y);
        o.z = f2bf(v[j * 4 + 2] * rr * w4.z);
        o.w = f2bf(v[j * 4 + 3] * rr * w4.w);
        *(ushort4*)&Yb[(size_t)t * kI + i] = o;
    }
}

extern "C" void kernel_launch(void* const* d_in, const int* in_sizes, int n_in,
                              void* d_out, int out_size, void* d_ws, size_t ws_size,
                              hipStream_t stream)
{
    const float* x       = (const float*)d_in[0];
    const float* W_in    = (const float*)d_in[1];
    const float* conv_w  = (const float*)d_in[2];
    const float* conv_b  = (const float*)d_in[3];
    const float* dt_bias = (const float*)d_in[4];
    const float* A_log   = (const float*)d_in[5];
    const float* Dp      = (const float*)d_in[6];
    const float* norm_w  = (const float*)d_in[7];
    const float* W_out   = (const float*)d_in[8];
    float* out = (float*)d_out;

    // workspace ~139.5 MB. Alias timeline:
    //   XT region: xb (pre-projGEMM) -> XT (conv..ssd) -> Wob (out GEMM)
    //   prev/Y region: Wb (pre-projGEMM) -> prev+states/Y -> Yb over prev
    float* ws   = (float*)d_ws;
    float* proj = ws;                                       // 2048*8512 f
    unsigned short* XT  = (unsigned short*)(proj + (size_t)kS * kProj);  // 4096*2048
    unsigned short* Bg  = XT + (size_t)kI * kS;             // 2048*128
    unsigned short* Btg = Bg + (size_t)kS * kN;             // 128*2048
    unsigned short* Cg  = Btg + (size_t)kN * kS;            // 2048*128
    float* dtb  = (float*)(Cg + (size_t)kS * kN);           // 2048*64
    float* acum = dtb + (size_t)kS * kH;                    // 2048*64
    float* prev = acum + (size_t)kS * kH;                   // 4,194,304 f
    float* Y    = prev + (size_t)kNC * kH * kP * kN;        // 8,388,608 f
    float* states = Y;
    unsigned short* xb  = XT;                               // early alias
    unsigned short* Wb  = (unsigned short*)prev;            // early (8.7M f < 12.6M)
    unsigned short* Yb  = (unsigned short*)prev;            // late
    unsigned short* Wob = XT;                               // late

    dim3 blk(256);
    const int NtP = (kProj + 127) / 128;   // 67
    const int NtO = kHID / 128;            // 16
    cast_bf16_k<<<(kS * kHID) / 2048, blk, 0, stream>>>(x, xb);
    cast_bf16_k<<<(kProj * kHID) / 2048, blk, 0, stream>>>(W_in, Wb);
    gemm_bt_bf16<<<NtP * 16, blk, 0, stream>>>(xb, Wb, proj, kS, kProj, kHID);
    conv_silu2_k<<<68 * 8, blk, 0, stream>>>(proj, conv_w, conv_b, XT, Bg, Btg, Cg);
    dt_cumsum_k<<<kNC * kH, blk, 0, stream>>>(proj, dt_bias, A_log, dtb, acum);
    states2_k<<<kNC * kH, blk, 0, stream>>>(XT, Btg, dtb, acum, states);
    scan_k<<<kH * 8, blk, 0, stream>>>(states, acum, prev);
    ssd_y4_k<<<kNC * kH * 4, blk, 0, stream>>>(Cg, Bg, XT, dtb, acum, prev, Dp, Y);
    rmsnorm_gate_k<<<kS, blk, 0, stream>>>(Y, proj, norm_w, Yb);
    cast_bf16_k<<<(kHID * kI) / 2048, blk, 0, stream>>>(W_out, Wob);
    gemm_bt_bf16<<<NtO * 16, blk, 0, stream>>>(Yb, Wob, out, kS, kHID, kI);
}